// Round 3
// baseline (11590.379 us; speedup 1.0000x reference)
//
#include <hip/hip_runtime.h>
#include <cstdint>
#include <cstddef>

#define LSEQ 8192
#define NT   34
#define NP   36
#define SCH  64
#define CCH  128
#define F_L2E 1.4426950408889634f
#define F_LN2 0.6931471805599453f

#if __has_builtin(__builtin_amdgcn_sdot4)
#define DOT4(a,b,c) __builtin_amdgcn_sdot4((a),(b),(c),false)
#else
__device__ __forceinline__ int dot4_fb(int a,int b,int c){
  c += (int)(signed char)(a & 0xff)        * (int)(signed char)(b & 0xff);
  c += (int)(signed char)((a>>8) & 0xff)   * (int)(signed char)((b>>8) & 0xff);
  c += (int)(signed char)((a>>16) & 0xff)  * (int)(signed char)((b>>16) & 0xff);
  c += (a>>24) * (b>>24);
  return c;
}
#define DOT4(a,b,c) dot4_fb((a),(b),(c))
#endif

__device__ __forceinline__ float ex2(float x){
#if __has_builtin(__builtin_amdgcn_exp2f)
  return __builtin_amdgcn_exp2f(x);
#else
  return exp2f(x);
#endif
}
__device__ __forceinline__ float lg2(float x){
#if __has_builtin(__builtin_amdgcn_logf)
  return __builtin_amdgcn_logf(x);   // v_log_f32 = log2
#else
  return __log2f(x);
#endif
}

__device__ __forceinline__ float sigf(float x){
  return __fdividef(1.f, 1.f + ex2(-F_L2E * x));
}
__device__ __forceinline__ float tanhf_fast(float x){
  return 1.f - __fdividef(2.f, ex2(2.f * F_L2E * x) + 1.f);
}

// barrier without the vmcnt(0) drain: LDS-only fence + s_barrier.
__device__ __forceinline__ void barrier_lds(){
  asm volatile("s_waitcnt lgkmcnt(0)\n\ts_barrier" ::: "memory");
}

// ---------------------------------------------------------------------------
// Kernel 1: quantize Whh (both dirs) to int8 with per-row scale.
// ---------------------------------------------------------------------------
__global__ void k_quant(const float* __restrict__ Whh_f,
                        const float* __restrict__ Whh_b,
                        int* __restrict__ Wq, float* __restrict__ fac){
  int bid = blockIdx.x;
  int dir = bid >> 10;
  int r   = bid & 1023;
  int i   = threadIdx.x;           // 0..63
  const float* W = (dir ? Whh_b : Whh_f) + r * 256 + i * 4;
  float w0 = W[0], w1 = W[1], w2 = W[2], w3 = W[3];
  float m = fmaxf(fmaxf(fabsf(w0), fabsf(w1)), fmaxf(fabsf(w2), fabsf(w3)));
  for (int s = 32; s; s >>= 1) m = fmaxf(m, __shfl_xor(m, s));
  float scale = (m > 0.f) ? m / 127.f : 1.f;
  float inv = __fdividef(1.f, scale);
  int q0 = (int)rintf(w0 * inv), q1 = (int)rintf(w1 * inv);
  int q2 = (int)rintf(w2 * inv), q3 = (int)rintf(w3 * inv);
  q0 = max(-127, min(127, q0)); q1 = max(-127, min(127, q1));
  q2 = max(-127, min(127, q2)); q3 = max(-127, min(127, q3));
  int p = (q0 & 255) | ((q1 & 255) << 8) | ((q2 & 255) << 16) | ((q3 & 255) << 24);
  Wq[(dir << 16) + (r << 6) + i] = p;
  if (i == 0) fac[(dir << 10) + r] = scale * (1.f / 127.f);
}

// ---------------------------------------------------------------------------
// Kernel 2: G[t][r] = b[r] + sum_e embed[words[t]][e] * Wih[r][e]
// ---------------------------------------------------------------------------
__global__ void k_gproj(const int* __restrict__ words,
                        const float* __restrict__ embed,
                        const float* __restrict__ Wih_f, const float* __restrict__ b_f,
                        const float* __restrict__ Wih_b, const float* __restrict__ b_b,
                        float* __restrict__ G_f, float* __restrict__ G_b){
  int dir = blockIdx.y;
  const float* Wih = dir ? Wih_b : Wih_f;
  const float* bb  = dir ? b_b  : b_f;
  float* G = dir ? G_b : G_f;
  int t0 = blockIdx.x * 16;
  __shared__ __align__(16) float X[16 * 256];
  for (int idx = threadIdx.x; idx < 16 * 256; idx += 256) {
    int tt = idx >> 8, e = idx & 255;
    X[idx] = embed[(size_t)words[t0 + tt] * 256 + e];
  }
  __syncthreads();
  const float4* X4 = (const float4*)X;
  for (int rb = 0; rb < 4; rb++) {
    int r = rb * 256 + threadIdx.x;
    float bv = bb[r];
    float acc[16];
#pragma unroll
    for (int tt = 0; tt < 16; tt++) acc[tt] = bv;
    const float4* W4 = (const float4*)(Wih + (size_t)r * 256);
    for (int eb = 0; eb < 64; eb++) {
      float4 w = W4[eb];
#pragma unroll
      for (int tt = 0; tt < 16; tt++) {
        float4 x = X4[tt * 64 + eb];
        acc[tt] += w.x * x.x + w.y * x.y + w.z * x.z + w.w * x.w;
      }
    }
    for (int tt = 0; tt < 16; tt++)
      G[(size_t)(t0 + tt) * 1024 + r] = acc[tt];
  }
}

// ---------------------------------------------------------------------------
// Kernel 3: LSTM recurrences. block 0 = forward, block 1 = backward.
// 512 threads, 2 weight rows per thread. Three structural changes vs R2:
//  (1) weights held as 128 INDIVIDUAL int regs (no int4 tuples -> no aligned-
//      quad fragmentation) + waves_per_eu(2,2) so the allocator has no
//      occupancy incentive to shunt them into AGPRs (R0/R2: VGPR_Count 84 <
//      128 weight regs => AGPR-resident, +1 v_accvgpr_read per dot = +512
//      VALU cyc/SIMD/step).
//  (2) h broadcast via ONE ds_read_b32/lane + v_readlane -> sdot4's SGPR
//      operand, replacing 16 ds_read_b128 broadcasts/thread (128 wave-instrs
//      /CU/step on the LDS pipe).
//  (3) G prefetch 4 steps deep: time loop unrolled x4 with 4 register sets;
//      loads for t+4 are issued into the registers just consumed, first use
//      4 steps (~3500 cyc) later -> no end-of-step vmcnt stall.
// Gate pairing in-wave as R2 (verified correct): unit u = tid>>1, even lane
// owns (i,f) rows, odd lane (g,o); two __shfl_xor(.,1) exchange. ONE barrier
// per step (h8 double-buffered).
// ---------------------------------------------------------------------------
__global__
__attribute__((amdgpu_flat_work_group_size(512, 512), amdgpu_waves_per_eu(2, 2)))
void k_lstm(const int* __restrict__ Wq,
            const float* __restrict__ fac,
            const float* __restrict__ G_f,
            const float* __restrict__ G_b,
            float* __restrict__ hf,
            float* __restrict__ hb){
  int dir = blockIdx.x;
  const int4* Wq4 = (const int4*)(Wq + (dir << 16));
  const float* facp = fac + (dir << 10);
  const float* G = dir ? G_b : G_f;
  float* hout = dir ? hb : hf;
  int tid  = threadIdx.x;
  int lane = tid & 63;
  int u    = tid >> 1;           // hidden unit 0..255
  int par  = tid & 1;            // 0: (i,f) rows; 1: (g,o) rows
  int r0   = u + par * 512;      // i-row or g-row
  int r1   = r0 + 256;           // f-row or o-row

  __shared__ __align__(16) int h8[2][64];   // 2 x 256 int8 h values

  // weights as 128 individual int registers
  int wAr[64], wBr[64];
#pragma unroll
  for (int i = 0; i < 16; i++) {
    int4 va = Wq4[r0 * 16 + i];
    int4 vb = Wq4[r1 * 16 + i];
    wAr[4*i+0] = va.x; wAr[4*i+1] = va.y; wAr[4*i+2] = va.z; wAr[4*i+3] = va.w;
    wBr[4*i+0] = vb.x; wBr[4*i+1] = vb.y; wBr[4*i+2] = vb.z; wBr[4*i+3] = vb.w;
  }
  float fA = facp[r0], fB = facp[r1];
  if (tid < 64) h8[0][tid] = 0;
  float c = 0.f;

  // 4-deep pipeline of G gate-projection pairs: ga->t, gb->t+1, gc->t+2, gd->t+3
  float ga0, ga1, gb0, gb1, gc0, gc1, gd0, gd1;
  {
    int tm0 = dir ? 8191 : 0;
    int tm1 = dir ? 8190 : 1;
    int tm2 = dir ? 8189 : 2;
    int tm3 = dir ? 8188 : 3;
    const float* p;
    p = G + (size_t)tm0 * 1024; ga0 = p[r0]; ga1 = p[r1];
    p = G + (size_t)tm1 * 1024; gb0 = p[r0]; gb1 = p[r1];
    p = G + (size_t)tm2 * 1024; gc0 = p[r0]; gc1 = p[r1];
    p = G + (size_t)tm3 * 1024; gd0 = p[r0]; gd1 = p[r1];
  }
  __syncthreads();

  auto step = [&](int t, const int* bufR, int* bufW, float& g0, float& g1) {
    // consume this step's G values (loaded 4 steps ago -> vmcnt satisfied)
    float cur0 = g0, cur1 = g1;
    // issue loads for t+4 into the just-freed registers; first use is the
    // gate phase 4 steps from now.
    {
      int tn = t + 4; if (tn > 8191) tn = 8191;
      int time2 = dir ? (8191 - tn) : tn;
      const float* p = G + (size_t)time2 * 1024;
      g0 = p[r0]; g1 = p[r1];
    }
    // h broadcast: one conflict-free ds_read_b32 per lane, then readlane.
    int hv = bufR[lane];
    int accA = 0, accB = 0;
#pragma unroll
    for (int j = 0; j < 64; j++) {
      int hs = __builtin_amdgcn_readlane(hv, j);
      accA = DOT4(wAr[j], hs, accA);
      accB = DOT4(wBr[j], hs, accB);
    }
    float vA = (float)accA * fA + cur0;   // even: i-pre, odd: g-pre
    float vB = (float)accB * fB + cur1;   // even: f-pre, odd: o-pre
    float rA = __shfl_xor(vA, 1);
    float rB = __shfl_xor(vB, 1);
    float gi = par ? rA : vA;
    float gf = par ? rB : vB;
    float gg = par ? vA : rA;
    float go = par ? vB : rB;
    float is = sigf(gi), fs = sigf(gf);
    float gt = tanhf_fast(gg), os = sigf(go);
    c = fs * c + is * gt;                 // both lanes of pair track same c
    float h = os * tanhf_fast(c);
    if (par == 0) {
      int time = dir ? (8191 - t) : t;
      hout[(size_t)time * 256 + u] = h;
      ((signed char*)bufW)[u] = (signed char)(int)rintf(h * 127.f);
    }
    barrier_lds();
  };

  for (int t = 0; t < 8192; t += 4) {
    step(t,     h8[0], h8[1], ga0, ga1);
    step(t + 1, h8[1], h8[0], gb0, gb1);
    step(t + 2, h8[0], h8[1], gc0, gc1);
    step(t + 3, h8[1], h8[0], gd0, gd1);
  }
}

// ---------------------------------------------------------------------------
// Kernel 4: feats = [hf | hb] @ W_out.T + b_out.
// ---------------------------------------------------------------------------
__global__ void k_feats(const float* __restrict__ hf, const float* __restrict__ hb,
                        const float* __restrict__ W_out, const float* __restrict__ b_out,
                        float* __restrict__ feats){
  int t0 = blockIdx.x * 16;
  for (int oi = threadIdx.x; oi < 16 * NT; oi += 256) {
    int tt = oi / NT;
    int tag = oi - tt * NT;
    int t = t0 + tt;
    const float4* w4 = (const float4*)(W_out + (size_t)tag * 512);
    const float4* a4 = (const float4*)(hf + (size_t)t * 256);
    const float4* c4 = (const float4*)(hb + (size_t)t * 256);
    float acc = b_out[tag];
    for (int k = 0; k < 64; k++) {
      float4 w = w4[k]; float4 h = a4[k];
      acc += w.x * h.x + w.y * h.y + w.z * h.z + w.w * h.w;
    }
    for (int k = 0; k < 64; k++) {
      float4 w = w4[64 + k]; float4 h = c4[k];
      acc += w.x * h.x + w.y * h.y + w.z * h.z + w.w * h.w;
    }
    feats[(size_t)t * NT + tag] = acc;
  }
}

// ---------------------------------------------------------------------------
// CRF as a chunked associative scan in the (lse,+) semiring, log2-domain.
// alpha: M_t[j][i] = λ(tr[j][i] + feat_t[j]);  alpha_t = M_t ⊗ alpha_{t-1}
// beta : N_t[j][i] = λ(tr[i][j] + feat_{t+1}[i]); beta_t = N_t ⊗ beta_{t+1},
//        N_{L-1} = identity, virtual beta_L[j] = lse_i λ tr[i][j].
// Phase 1: per-chunk matrix products (128 chunks x 2 dirs, parallel).
// Phase 2: sequential matvec prefix over 128 chunk products (2 blocks).
// Phase 3: per-chunk vector re-scan emitting wsA/wsB (parallel).
// ---------------------------------------------------------------------------
__global__ __launch_bounds__(320) void k_crf_p1(const float* __restrict__ feats,
                                                const float* __restrict__ trans,
                                                float* __restrict__ Pg,
                                                float* __restrict__ rmaxG){
  int dir = blockIdx.x >> 7;
  int c   = blockIdx.x & (CCH - 1);
  int tid = threadIdx.x;
  int t0  = c * SCH;

  __shared__ __align__(16) float TRM[NT * NP];
  __shared__ float Fe[(SCH + 1) * NT];
  __shared__ __align__(16) float Pbuf[2][NT * NP];
  __shared__ float CM[NP];
  __shared__ float RMs[NT];

  for (int idx = tid; idx < NT * NT; idx += 320) {
    int j = idx / NT, k = idx - j * NT;
    float v = (dir == 0) ? trans[j * NT + k] : trans[k * NT + j];
    TRM[j * NP + k] = v * F_L2E;
  }
  for (int idx = tid; idx < (SCH + 1) * NT; idx += 320) {
    int s = idx / NT, j = idx - s * NT;
    int t = t0 + s; if (t > LSEQ - 1) t = LSEQ - 1;
    Fe[idx] = feats[(size_t)t * NT + j] * F_L2E;
  }
  for (int idx = tid; idx < NT * NP; idx += 320) {
    int k = idx / NP, i = idx - k * NP;
    Pbuf[0][idx] = (i < NT && i == k) ? 0.f : -1e30f;
  }
  if (tid < NP) CM[tid] = (tid < NT) ? 0.f : -1e30f;
  __syncthreads();
  if (tid < NT) {
    float m = -3e38f;
    for (int k = 0; k < NT; k++) m = fmaxf(m, TRM[tid * NP + k]);
    RMs[tid] = m;
  }
  __syncthreads();
  for (int idx = tid; idx < NT * NT; idx += 320) {
    int j = idx / NT, k = idx - j * NT;
    TRM[j * NP + k] -= RMs[j];
  }
  __syncthreads();

  int cur = 0;
  int j = tid / 9, g = tid - (tid / 9) * 9;
  bool act = (tid < 306);
  int i0 = 4 * g;

  for (int s = 0; s < SCH; s++) {
    int t = (dir == 0) ? (t0 + s) : (t0 + SCH - 1 - s);
    if (dir == 1 && t == LSEQ - 1) continue;   // identity factor at t=L-1
    const float* Pc = Pbuf[cur];
    float* Pn = Pbuf[cur ^ 1];
    if (act) {
      float cm0 = CM[i0], cm1 = CM[i0 + 1], cm2 = CM[i0 + 2], cm3 = CM[i0 + 3];
      float s0 = 0, s1 = 0, s2 = 0, s3 = 0;
      const float* trp = TRM + j * NP;
      const float* fep = Fe + (t + 1 - t0) * NT;   // only read when dir==1
#pragma unroll
      for (int k = 0; k < NT; k++) {
        float trv = trp[k];
        if (dir == 1) trv += fep[k];
        float4 p = *(const float4*)&Pc[k * NP + i0];
        s0 += ex2(trv + p.x - cm0);
        s1 += ex2(trv + p.y - cm1);
        s2 += ex2(trv + p.z - cm2);
        s3 += ex2(trv + p.w - cm3);
      }
      float base = RMs[j] + ((dir == 0) ? Fe[(t - t0) * NT + j] : 0.f);
      float4 o;
      o.x = base + cm0 + lg2(s0);
      o.y = base + cm1 + lg2(s1);
      o.z = (i0 + 2 < NT) ? (base + cm2 + lg2(s2)) : -1e30f;
      o.w = (i0 + 3 < NT) ? (base + cm3 + lg2(s3)) : -1e30f;
      *(float4*)&Pn[j * NP + i0] = o;
    }
    __syncthreads();
    if (tid < NP) {
      float m = -3e38f;
      const float* col = Pn + tid;
      for (int k = 0; k < NT; k++) m = fmaxf(m, col[k * NP]);
      CM[tid] = m;
    }
    cur ^= 1;
    __syncthreads();
  }

  const float* Pf = Pbuf[cur];
  size_t base = (size_t)((dir << 7) + c) * (NT * NP);
  for (int idx = tid; idx < NT * NP; idx += 320)
    Pg[base + idx] = Pf[idx];
  if (tid < NT) {
    float m = -3e38f;
    for (int i = 0; i < NT; i++) m = fmaxf(m, Pf[tid * NP + i]);
    rmaxG[((dir << 7) + c) * NT + tid] = m;
  }
}

__global__ void k_crf_p2(const float* __restrict__ trans,
                         const float* __restrict__ Pg,
                         const float* __restrict__ rmaxG,
                         float* __restrict__ vIn){
  int dir = blockIdx.x;
  int lane = threadIdx.x;           // 64, single wave
  bool a = (lane < NT);
  int j = a ? lane : 0;
  __shared__ float V[NP];

  float v;
  if (dir == 0) {
    v = (lane == 32) ? 0.f : -10000.f * F_L2E;
  } else {
    float m = -3e38f;
    for (int i = 0; i < NT; i++) m = fmaxf(m, trans[i * NT + j]);
    float s = 0.f;
    for (int i = 0; i < NT; i++) s += ex2((trans[i * NT + j] - m) * F_L2E);
    v = m * F_L2E + lg2(s);
  }
  if (lane < NP) V[lane] = -1e30f;
  barrier_lds();
  if (a) V[j] = v;
  barrier_lds();
  float vm = a ? v : -3e38f;
  for (int off = 32; off; off >>= 1) vm = fmaxf(vm, __shfl_xor(vm, off));

  if (a) {
    int c0 = (dir == 0) ? 0 : (CCH - 1);
    vIn[((size_t)(dir << 7) + c0) * NP + j] = v;
  }

  for (int it = 0; it < CCH - 1; it++) {
    int c = (dir == 0) ? it : (CCH - 1 - it);
    const float* row = Pg + ((size_t)(dir << 7) + c) * (NT * NP) + j * NP;
    float rm = rmaxG[((dir << 7) + c) * NT + j];
    float m = rm + vm;
    float s = 0.f;
#pragma unroll
    for (int k = 0; k < NP; k += 4) {
      float4 p = *(const float4*)&row[k];
      s += ex2(p.x + V[k]     - m);
      s += ex2(p.y + V[k + 1] - m);
      s += ex2(p.z + V[k + 2] - m);
      s += ex2(p.w + V[k + 3] - m);
    }
    float nv = m + lg2(s);
    if (a) V[j] = nv;
    barrier_lds();
    float x = a ? nv : -3e38f;
    for (int off = 32; off; off >>= 1) x = fmaxf(x, __shfl_xor(x, off));
    vm = x;
    int cn = (dir == 0) ? (c + 1) : (c - 1);
    if (a) vIn[((size_t)(dir << 7) + cn) * NP + j] = nv;
  }
}

__global__ void k_crf_p3(const float* __restrict__ feats,
                         const float* __restrict__ trans,
                         const float* __restrict__ vIn,
                         float* __restrict__ wsA,
                         float* __restrict__ wsB){
  int dir = blockIdx.x >> 7;
  int c   = blockIdx.x & (CCH - 1);
  int lane = threadIdx.x;           // 64, single wave
  int t0 = c * SCH;
  bool a = (lane < NT);
  int j = a ? lane : 0;
  __shared__ float A[NP];
  __shared__ float U[NP];

  float trr[NT];
  float rm = -3e38f;
#pragma unroll
  for (int k = 0; k < NT; k++) {
    float vv = (dir == 0) ? trans[j * NT + k] : trans[k * NT + j];
    trr[k] = vv * F_L2E;
    rm = fmaxf(rm, trr[k]);
  }
  if (lane < NP) { A[lane] = -1e30f; U[lane] = -1e30f; }
  float v0 = vIn[((size_t)(dir << 7) + c) * NP + j];
  barrier_lds();
  if (a) A[j] = v0;
  barrier_lds();
  float am = a ? v0 : -3e38f;
  for (int off = 32; off; off >>= 1) am = fmaxf(am, __shfl_xor(am, off));

  if (dir == 0) {
    float fe = feats[(size_t)t0 * NT + j] * F_L2E;
    for (int s = 0; s < SCH; s++) {
      int t = t0 + s;
      int tn = (t + 1 < LSEQ) ? t + 1 : LSEQ - 1;
      float fe_n = feats[(size_t)tn * NT + j] * F_L2E;
      float m = rm + am;
      float ss = 0.f;
#pragma unroll
      for (int k = 0; k < NT; k++) ss += ex2(trr[k] + A[k] - m);
      float out = m + lg2(ss) + fe;
      if (a) wsA[(size_t)t * NT + j] = out * F_LN2;
      if (a) A[j] = out;
      barrier_lds();
      float x = a ? out : -3e38f;
      for (int off = 32; off; off >>= 1) x = fmaxf(x, __shfl_xor(x, off));
      am = x;
      fe = fe_n;
    }
  } else {
    float b = v0;                    // beta_{t+1}, per-lane register
    int tfirst = t0 + SCH; if (tfirst > LSEQ - 1) tfirst = LSEQ - 1;
    float fe = feats[(size_t)tfirst * NT + j] * F_L2E;   // feat_{t+1} for first step
    for (int s = 0; s < SCH; s++) {
      int t = t0 + SCH - 1 - s;
      float fe_n = feats[(size_t)t * NT + j] * F_L2E;    // next step's feat_{t+1}
      float out;
      if (t == LSEQ - 1) {
        out = b;                     // identity factor
      } else {
        if (a) U[j] = b + fe;
        barrier_lds();
        float um = a ? U[j] : -3e38f;
        for (int off = 32; off; off >>= 1) um = fmaxf(um, __shfl_xor(um, off));
        float m = rm + um;
        float ss = 0.f;
#pragma unroll
        for (int k = 0; k < NT; k++) ss += ex2(trr[k] + U[k] - m);
        out = m + lg2(ss);
        barrier_lds();
      }
      if (a) wsB[(size_t)t * NT + j] = out * F_LN2;
      b = out;
      fe = fe_n;
    }
  }
}

// ---------------------------------------------------------------------------
// Kernel: score = alpha + beta; tags = argmax.
// ---------------------------------------------------------------------------
__global__ void k_finish(const float* __restrict__ wsA, const float* __restrict__ wsB,
                         float* __restrict__ out){
  int t = blockIdx.x * 256 + threadIdx.x;
  float m = -3e38f; int bi = 0;
  for (int i = 0; i < NT; i++) {
    float sc = wsA[(size_t)t * NT + i] + wsB[(size_t)t * NT + i];
    out[(size_t)t * NT + i] = sc;
    if (sc > m) { m = sc; bi = i; }
  }
  out[(size_t)LSEQ * NT + t] = (float)bi;
}

// ---------------------------------------------------------------------------
extern "C" void kernel_launch(void* const* d_in, const int* in_sizes, int n_in,
                              void* d_out, int out_size, void* d_ws, size_t ws_size,
                              hipStream_t stream) {
  const int*   words  = (const int*)  d_in[0];
  const float* embed  = (const float*)d_in[1];
  const float* Wih_f  = (const float*)d_in[2];
  const float* Whh_f  = (const float*)d_in[3];
  const float* b_f    = (const float*)d_in[4];
  const float* Wih_b  = (const float*)d_in[5];
  const float* Whh_b  = (const float*)d_in[6];
  const float* b_b    = (const float*)d_in[7];
  const float* W_out  = (const float*)d_in[8];
  const float* b_out  = (const float*)d_in[9];
  const float* trans  = (const float*)d_in[10];
  float* out = (float*)d_out;

  float* wsf = (float*)d_ws;
  size_t off = 0;
  float* G_f   = wsf + off; off += (size_t)LSEQ * 1024;
  float* G_b   = wsf + off; off += (size_t)LSEQ * 1024;
  float* hf    = wsf + off; off += (size_t)LSEQ * 256;
  float* hb    = wsf + off; off += (size_t)LSEQ * 256;
  float* feats = wsf + off; off += (size_t)LSEQ * NT + 16;
  float* wsA   = wsf + off; off += (size_t)LSEQ * NT + 16;
  float* wsB   = wsf + off; off += (size_t)LSEQ * NT + 16;
  float* fac   = wsf + off; off += 2048;
  int*   Wq    = (int*)(wsf + off); off += 2 * 1024 * 64;
  // CRF scan scratch overlaps G_f (dead after k_lstm)
  float* Pg    = G_f;                                   // 256 * 34*36
  float* rmaxG = G_f + 256 * (NT * NP);                 // 256 * 34
  float* vIn   = rmaxG + 256 * NT + 32;                 // 256 * 36

  k_quant<<<2048, 64, 0, stream>>>(Whh_f, Whh_b, Wq, fac);
  k_gproj<<<dim3(512, 2), 256, 0, stream>>>(words, embed, Wih_f, b_f, Wih_b, b_b, G_f, G_b);
  k_lstm<<<2, 512, 0, stream>>>(Wq, fac, G_f, G_b, hf, hb);
  k_feats<<<512, 256, 0, stream>>>(hf, hb, W_out, b_out, feats);
  k_crf_p1<<<256, 320, 0, stream>>>(feats, trans, Pg, rmaxG);
  k_crf_p2<<<2, 64, 0, stream>>>(trans, Pg, rmaxG, vIn);
  k_crf_p3<<<256, 64, 0, stream>>>(feats, trans, vIn, wsA, wsB);
  k_finish<<<32, 256, 0, stream>>>(wsA, wsB, out);
}

// Round 5
// 9453.656 us; speedup vs baseline: 1.2260x; 1.2260x over previous
//
#include <hip/hip_runtime.h>
#include <cstdint>
#include <cstddef>

#define LSEQ 8192
#define NT   34
#define NP   36
#define SCH  64
#define CCH  128
#define F_L2E 1.4426950408889634f
#define F_LN2 0.6931471805599453f

#if __has_builtin(__builtin_amdgcn_sdot4)
#define DOT4(a,b,c) __builtin_amdgcn_sdot4((a),(b),(c),false)
#else
__device__ __forceinline__ int dot4_fb(int a,int b,int c){
  c += (int)(signed char)(a & 0xff)        * (int)(signed char)(b & 0xff);
  c += (int)(signed char)((a>>8) & 0xff)   * (int)(signed char)((b>>8) & 0xff);
  c += (int)(signed char)((a>>16) & 0xff)  * (int)(signed char)((b>>16) & 0xff);
  c += (a>>24) * (b>>24);
  return c;
}
#define DOT4(a,b,c) dot4_fb((a),(b),(c))
#endif

#if __has_builtin(__builtin_amdgcn_global_load_lds)
#define HAS_GLL 1
#else
#define HAS_GLL 0
#endif

__device__ __forceinline__ float ex2(float x){
#if __has_builtin(__builtin_amdgcn_exp2f)
  return __builtin_amdgcn_exp2f(x);
#else
  return exp2f(x);
#endif
}
__device__ __forceinline__ float lg2(float x){
#if __has_builtin(__builtin_amdgcn_logf)
  return __builtin_amdgcn_logf(x);   // v_log_f32 = log2
#else
  return __log2f(x);
#endif
}

__device__ __forceinline__ float sigf(float x){
  return __fdividef(1.f, 1.f + ex2(-F_L2E * x));
}
__device__ __forceinline__ float tanhf_fast(float x){
  return 1.f - __fdividef(2.f, ex2(2.f * F_L2E * x) + 1.f);
}

// quad butterfly reduce (int add) on the VALU via DPP quad_perm --
// deliberately NOT __shfl (ds_swizzle = LDS pipe; that pipe is the bottleneck).
__device__ __forceinline__ int qreduce(int x){
#if __has_builtin(__builtin_amdgcn_mov_dpp)
  x += __builtin_amdgcn_mov_dpp(x, 0xB1, 0xF, 0xF, true);  // quad_perm [1,0,3,2]
  x += __builtin_amdgcn_mov_dpp(x, 0x4E, 0xF, 0xF, true);  // quad_perm [2,3,0,1]
#else
  x += __shfl_xor(x, 1);
  x += __shfl_xor(x, 2);
#endif
  return x;
}

// barrier without the vmcnt(0) drain: LDS-only fence + s_barrier.
__device__ __forceinline__ void barrier_lds(){
  asm volatile("s_waitcnt lgkmcnt(0)\n\ts_barrier" ::: "memory");
}

// ---------------------------------------------------------------------------
// Kernel 1: quantize Whh (both dirs) to int8 with per-row scale.
// ---------------------------------------------------------------------------
__global__ void k_quant(const float* __restrict__ Whh_f,
                        const float* __restrict__ Whh_b,
                        int* __restrict__ Wq, float* __restrict__ fac){
  int bid = blockIdx.x;
  int dir = bid >> 10;
  int r   = bid & 1023;
  int i   = threadIdx.x;           // 0..63
  const float* W = (dir ? Whh_b : Whh_f) + r * 256 + i * 4;
  float w0 = W[0], w1 = W[1], w2 = W[2], w3 = W[3];
  float m = fmaxf(fmaxf(fabsf(w0), fabsf(w1)), fmaxf(fabsf(w2), fabsf(w3)));
  for (int s = 32; s; s >>= 1) m = fmaxf(m, __shfl_xor(m, s));
  float scale = (m > 0.f) ? m / 127.f : 1.f;
  float inv = __fdividef(1.f, scale);
  int q0 = (int)rintf(w0 * inv), q1 = (int)rintf(w1 * inv);
  int q2 = (int)rintf(w2 * inv), q3 = (int)rintf(w3 * inv);
  q0 = max(-127, min(127, q0)); q1 = max(-127, min(127, q1));
  q2 = max(-127, min(127, q2)); q3 = max(-127, min(127, q3));
  int p = (q0 & 255) | ((q1 & 255) << 8) | ((q2 & 255) << 16) | ((q3 & 255) << 24);
  Wq[(dir << 16) + (r << 6) + i] = p;
  if (i == 0) fac[(dir << 10) + r] = scale * (1.f / 127.f);
}

// ---------------------------------------------------------------------------
// Kernel 2: G[t][u*4+gate] = b[r] + sum_e embed[words[t]][e] * Wih[r][e]
// (gate-interleaved output layout so k_lstm reads one float4 per unit)
// ---------------------------------------------------------------------------
__global__ void k_gproj(const int* __restrict__ words,
                        const float* __restrict__ embed,
                        const float* __restrict__ Wih_f, const float* __restrict__ b_f,
                        const float* __restrict__ Wih_b, const float* __restrict__ b_b,
                        float* __restrict__ G_f, float* __restrict__ G_b){
  int dir = blockIdx.y;
  const float* Wih = dir ? Wih_b : Wih_f;
  const float* bb  = dir ? b_b  : b_f;
  float* G = dir ? G_b : G_f;
  int t0 = blockIdx.x * 16;
  __shared__ __align__(16) float X[16 * 256];
  for (int idx = threadIdx.x; idx < 16 * 256; idx += 256) {
    int tt = idx >> 8, e = idx & 255;
    X[idx] = embed[(size_t)words[t0 + tt] * 256 + e];
  }
  __syncthreads();
  const float4* X4 = (const float4*)X;
  for (int rb = 0; rb < 4; rb++) {
    int r = rb * 256 + threadIdx.x;      // gate rb, unit threadIdx.x
    float bv = bb[r];
    float acc[16];
#pragma unroll
    for (int tt = 0; tt < 16; tt++) acc[tt] = bv;
    const float4* W4 = (const float4*)(Wih + (size_t)r * 256);
    for (int eb = 0; eb < 64; eb++) {
      float4 w = W4[eb];
#pragma unroll
      for (int tt = 0; tt < 16; tt++) {
        float4 x = X4[tt * 64 + eb];
        acc[tt] += w.x * x.x + w.y * x.y + w.z * x.z + w.w * x.w;
      }
    }
    for (int tt = 0; tt < 16; tt++)
      G[(size_t)(t0 + tt) * 1024 + (threadIdx.x << 2) + rb] = acc[tt];
  }
}

// ---------------------------------------------------------------------------
// Kernel 3: LSTM recurrences. block 0 = forward, block 1 = backward.
// Decomposition: quad q owns 8 rows = all 4 gates of units {2q, 2q+1};
// lane kq = tid&3 handles a 64-element K-slice. Per-step LDS traffic per
// thread: 4x ds_read_b128 (64B h slice) + 1x ds_read_b128 (unit's G float4)
// vs the old 16x b128 full-vector broadcast -- the LDS pipe (12 cyc/b128,
// ~1536 cyc/step at 128 instrs) was the measured bottleneck of R0/R2.
// Quad reduction via DPP quad_perm (VALU), G staged into LDS in 4-step
// chunks (2x16KB, 32.5KB static LDS -- R4's 66KB exceeded the 64KB static
// limit and killed the module load) with global_load_lds and ONE vmcnt(0)
// per 4 steps. Zero per-step VMEM reads; one barrier per step.
// ---------------------------------------------------------------------------
__global__ __launch_bounds__(512, 2) void k_lstm(const int* __restrict__ Wq,
                                                 const float* __restrict__ fac,
                                                 const float* __restrict__ G_f,
                                                 const float* __restrict__ G_b,
                                                 float* __restrict__ hf,
                                                 float* __restrict__ hb){
  int dir = blockIdx.x;
  const int* Wqd = Wq + (dir << 16);
  const float* facp = fac + (dir << 10);
  const float* G = dir ? G_b : G_f;
  float* hout = dir ? hb : hf;
  int tid = threadIdx.x;
  int ln  = tid & 63;            // lane
  int wv  = tid >> 6;            // wave 0..7
  int q   = tid >> 2;            // quad 0..127
  int kq  = tid & 3;             // K-quarter 0..3
  int u   = (q << 1) + (tid & 1);  // unit this lane finalizes (lanes 2,3 mirror 0,1)

  __shared__ __align__(16) float GL[2][4 * 1024];   // 2 x 16KB G staging
  __shared__ __align__(16) int h8[2][64];           // 2 x 256 int8 h

  // weights: 8 rows x 16 ints (this lane's K-slice). row(m) = 2q+(m&1) + (m>>1)*256
  int4 w4[8][4];
#pragma unroll
  for (int g = 0; g < 4; g++) {
#pragma unroll
    for (int uu = 0; uu < 2; uu++) {
      int r = (q << 1) + uu + (g << 8);
      const int4* p = (const int4*)(Wqd + (r << 6) + (kq << 4));
      w4[g * 2 + uu][0] = p[0]; w4[g * 2 + uu][1] = p[1];
      w4[g * 2 + uu][2] = p[2]; w4[g * 2 + uu][3] = p[3];
    }
  }
  float fI = facp[u], fF = facp[u + 256], fG = facp[u + 512], fO = facp[u + 768];
  if (tid < 64) h8[0][tid] = 0;
  float c = 0.f;

  // stage chunk cn (4 timesteps = 16KB contiguous) into GL[cn&1].
  // Per wave: 2KB via 2 global_load_lds width-16 (LDS dst wave-uniform,
  // HW adds lane*16; global src per-lane).
  auto stage = [&](int cn) {
    int half = cn & 1;
    int gt0 = dir ? (8191 - (cn * 4 + 3)) : (cn * 4);
    const char* src = (const char*)(G + (size_t)gt0 * 1024) + (wv << 11) + (ln << 4);
    char* dst = (char*)&GL[half][0] + (wv << 11);
#pragma unroll
    for (int i = 0; i < 2; i++) {
#if HAS_GLL
      __builtin_amdgcn_global_load_lds(
          (const __attribute__((address_space(1))) unsigned int*)(src + (i << 10)),
          (__attribute__((address_space(3))) unsigned int*)(dst + (i << 10)),
          16, 0, 0);
#else
      *(float4*)(dst + (i << 10) + (ln << 4)) = *(const float4*)(src + (i << 10));
#endif
    }
  };

  auto step = [&](int t, const float* Grow, const int* bufR, int* bufW) {
    // this lane's 64B h slice: 4x ds_read_b128, 16-lane broadcast groups
    const int4* hs = (const int4*)((const char*)bufR + (kq << 6));
    int4 h0 = hs[0], h1 = hs[1], h2 = hs[2], h3 = hs[3];
    int acc[8];
#pragma unroll
    for (int m = 0; m < 8; m++) {
      int a = 0;
      a = DOT4(w4[m][0].x, h0.x, a); a = DOT4(w4[m][0].y, h0.y, a);
      a = DOT4(w4[m][0].z, h0.z, a); a = DOT4(w4[m][0].w, h0.w, a);
      a = DOT4(w4[m][1].x, h1.x, a); a = DOT4(w4[m][1].y, h1.y, a);
      a = DOT4(w4[m][1].z, h1.z, a); a = DOT4(w4[m][1].w, h1.w, a);
      a = DOT4(w4[m][2].x, h2.x, a); a = DOT4(w4[m][2].y, h2.y, a);
      a = DOT4(w4[m][2].z, h2.z, a); a = DOT4(w4[m][2].w, h2.w, a);
      a = DOT4(w4[m][3].x, h3.x, a); a = DOT4(w4[m][3].y, h3.y, a);
      a = DOT4(w4[m][3].z, h3.z, a); a = DOT4(w4[m][3].w, h3.w, a);
      acc[m] = a;
    }
    // quad butterfly: all 4 lanes end with full 256-K sums (int, exact)
#pragma unroll
    for (int m = 0; m < 8; m++) acc[m] = qreduce(acc[m]);
    // lane parity selects its unit's accs (static indices + cndmask)
    int p = tid & 1;
    int aI = p ? acc[1] : acc[0];
    int aF = p ? acc[3] : acc[2];
    int aG = p ? acc[5] : acc[4];
    int aO = p ? acc[7] : acc[6];
    float4 gv = ((const float4*)Grow)[u];   // unit's (i,f,g,o) G values
    float ri = (float)aI * fI + gv.x;
    float rf = (float)aF * fF + gv.y;
    float rg = (float)aG * fG + gv.z;
    float ro = (float)aO * fO + gv.w;
    float is = sigf(ri), fs = sigf(rf);
    float gt = tanhf_fast(rg), os = sigf(ro);
    c = fs * c + is * gt;                   // lanes 2,3 mirror 0,1's c state
    float h = os * tanhf_fast(c);
    if ((tid & 3) < 2) {                    // one writer per unit
      int time = dir ? (8191 - t) : t;
      hout[(size_t)time * 256 + u] = h;     // queues; drained at chunk end
      ((signed char*)bufW)[u] = (signed char)(int)rintf(h * 127.f);
    }
  };

  // prologue: stage chunk 0, drain, sync
  stage(0);
  asm volatile("s_waitcnt vmcnt(0)" ::: "memory");
  __syncthreads();

  for (int cn = 0; cn < 2048; ++cn) {
    if (cn + 1 < 2048) stage(cn + 1);       // writes the OTHER half; WAR-safe
    const float* Hc = GL[cn & 1];
    int tb = cn << 2;
#pragma unroll
    for (int s = 0; s < 4; ++s) {
      int row = dir ? (3 - s) : s;
      const float* Grow = Hc + (row << 10);
      int t = tb + s;
      if ((s & 1) == 0) step(t, Grow, h8[0], h8[1]);
      else              step(t, Grow, h8[1], h8[0]);
      if (s == 3) {
        // chunk boundary: drain staging once per 4 steps (~3800 cyc of cover)
        asm volatile("s_waitcnt vmcnt(0) lgkmcnt(0)\n\ts_barrier" ::: "memory");
      } else {
        barrier_lds();
      }
    }
  }
}

// ---------------------------------------------------------------------------
// Kernel 4: feats = [hf | hb] @ W_out.T + b_out.
// ---------------------------------------------------------------------------
__global__ void k_feats(const float* __restrict__ hf, const float* __restrict__ hb,
                        const float* __restrict__ W_out, const float* __restrict__ b_out,
                        float* __restrict__ feats){
  int t0 = blockIdx.x * 16;
  for (int oi = threadIdx.x; oi < 16 * NT; oi += 256) {
    int tt = oi / NT;
    int tag = oi - tt * NT;
    int t = t0 + tt;
    const float4* w4 = (const float4*)(W_out + (size_t)tag * 512);
    const float4* a4 = (const float4*)(hf + (size_t)t * 256);
    const float4* c4 = (const float4*)(hb + (size_t)t * 256);
    float acc = b_out[tag];
    for (int k = 0; k < 64; k++) {
      float4 w = w4[k]; float4 h = a4[k];
      acc += w.x * h.x + w.y * h.y + w.z * h.z + w.w * h.w;
    }
    for (int k = 0; k < 64; k++) {
      float4 w = w4[64 + k]; float4 h = c4[k];
      acc += w.x * h.x + w.y * h.y + w.z * h.z + w.w * h.w;
    }
    feats[(size_t)t * NT + tag] = acc;
  }
}

// ---------------------------------------------------------------------------
// CRF as a chunked associative scan in the (lse,+) semiring, log2-domain.
// alpha: M_t[j][i] = λ(tr[j][i] + feat_t[j]);  alpha_t = M_t ⊗ alpha_{t-1}
// beta : N_t[j][i] = λ(tr[i][j] + feat_{t+1}[i]); beta_t = N_t ⊗ beta_{t+1},
//        N_{L-1} = identity, virtual beta_L[j] = lse_i λ tr[i][j].
// Phase 1: per-chunk matrix products (128 chunks x 2 dirs, parallel).
// Phase 2: sequential matvec prefix over 128 chunk products (2 blocks).
// Phase 3: per-chunk vector re-scan emitting wsA/wsB (parallel).
// ---------------------------------------------------------------------------
__global__ __launch_bounds__(320) void k_crf_p1(const float* __restrict__ feats,
                                                const float* __restrict__ trans,
                                                float* __restrict__ Pg,
                                                float* __restrict__ rmaxG){
  int dir = blockIdx.x >> 7;
  int c   = blockIdx.x & (CCH - 1);
  int tid = threadIdx.x;
  int t0  = c * SCH;

  __shared__ __align__(16) float TRM[NT * NP];
  __shared__ float Fe[(SCH + 1) * NT];
  __shared__ __align__(16) float Pbuf[2][NT * NP];
  __shared__ float CM[NP];
  __shared__ float RMs[NT];

  for (int idx = tid; idx < NT * NT; idx += 320) {
    int j = idx / NT, k = idx - j * NT;
    float v = (dir == 0) ? trans[j * NT + k] : trans[k * NT + j];
    TRM[j * NP + k] = v * F_L2E;
  }
  for (int idx = tid; idx < (SCH + 1) * NT; idx += 320) {
    int s = idx / NT, j = idx - s * NT;
    int t = t0 + s; if (t > LSEQ - 1) t = LSEQ - 1;
    Fe[idx] = feats[(size_t)t * NT + j] * F_L2E;
  }
  for (int idx = tid; idx < NT * NP; idx += 320) {
    int k = idx / NP, i = idx - k * NP;
    Pbuf[0][idx] = (i < NT && i == k) ? 0.f : -1e30f;
  }
  if (tid < NP) CM[tid] = (tid < NT) ? 0.f : -1e30f;
  __syncthreads();
  if (tid < NT) {
    float m = -3e38f;
    for (int k = 0; k < NT; k++) m = fmaxf(m, TRM[tid * NP + k]);
    RMs[tid] = m;
  }
  __syncthreads();
  for (int idx = tid; idx < NT * NT; idx += 320) {
    int j = idx / NT, k = idx - j * NT;
    TRM[j * NP + k] -= RMs[j];
  }
  __syncthreads();

  int cur = 0;
  int j = tid / 9, g = tid - (tid / 9) * 9;
  bool act = (tid < 306);
  int i0 = 4 * g;

  for (int s = 0; s < SCH; s++) {
    int t = (dir == 0) ? (t0 + s) : (t0 + SCH - 1 - s);
    if (dir == 1 && t == LSEQ - 1) continue;   // identity factor at t=L-1
    const float* Pc = Pbuf[cur];
    float* Pn = Pbuf[cur ^ 1];
    if (act) {
      float cm0 = CM[i0], cm1 = CM[i0 + 1], cm2 = CM[i0 + 2], cm3 = CM[i0 + 3];
      float s0 = 0, s1 = 0, s2 = 0, s3 = 0;
      const float* trp = TRM + j * NP;
      const float* fep = Fe + (t + 1 - t0) * NT;   // only read when dir==1
#pragma unroll
      for (int k = 0; k < NT; k++) {
        float trv = trp[k];
        if (dir == 1) trv += fep[k];
        float4 p = *(const float4*)&Pc[k * NP + i0];
        s0 += ex2(trv + p.x - cm0);
        s1 += ex2(trv + p.y - cm1);
        s2 += ex2(trv + p.z - cm2);
        s3 += ex2(trv + p.w - cm3);
      }
      float base = RMs[j] + ((dir == 0) ? Fe[(t - t0) * NT + j] : 0.f);
      float4 o;
      o.x = base + cm0 + lg2(s0);
      o.y = base + cm1 + lg2(s1);
      o.z = (i0 + 2 < NT) ? (base + cm2 + lg2(s2)) : -1e30f;
      o.w = (i0 + 3 < NT) ? (base + cm3 + lg2(s3)) : -1e30f;
      *(float4*)&Pn[j * NP + i0] = o;
    }
    __syncthreads();
    if (tid < NP) {
      float m = -3e38f;
      const float* col = Pn + tid;
      for (int k = 0; k < NT; k++) m = fmaxf(m, col[k * NP]);
      CM[tid] = m;
    }
    cur ^= 1;
    __syncthreads();
  }

  const float* Pf = Pbuf[cur];
  size_t base = (size_t)((dir << 7) + c) * (NT * NP);
  for (int idx = tid; idx < NT * NP; idx += 320)
    Pg[base + idx] = Pf[idx];
  if (tid < NT) {
    float m = -3e38f;
    for (int i = 0; i < NT; i++) m = fmaxf(m, Pf[tid * NP + i]);
    rmaxG[((dir << 7) + c) * NT + tid] = m;
  }
}

__global__ void k_crf_p2(const float* __restrict__ trans,
                         const float* __restrict__ Pg,
                         const float* __restrict__ rmaxG,
                         float* __restrict__ vIn){
  int dir = blockIdx.x;
  int lane = threadIdx.x;           // 64, single wave
  bool a = (lane < NT);
  int j = a ? lane : 0;
  __shared__ float V[NP];

  float v;
  if (dir == 0) {
    v = (lane == 32) ? 0.f : -10000.f * F_L2E;
  } else {
    float m = -3e38f;
    for (int i = 0; i < NT; i++) m = fmaxf(m, trans[i * NT + j]);
    float s = 0.f;
    for (int i = 0; i < NT; i++) s += ex2((trans[i * NT + j] - m) * F_L2E);
    v = m * F_L2E + lg2(s);
  }
  if (lane < NP) V[lane] = -1e30f;
  barrier_lds();
  if (a) V[j] = v;
  barrier_lds();
  float vm = a ? v : -3e38f;
  for (int off = 32; off; off >>= 1) vm = fmaxf(vm, __shfl_xor(vm, off));

  if (a) {
    int c0 = (dir == 0) ? 0 : (CCH - 1);
    vIn[((size_t)(dir << 7) + c0) * NP + j] = v;
  }

  for (int it = 0; it < CCH - 1; it++) {
    int c = (dir == 0) ? it : (CCH - 1 - it);
    const float* row = Pg + ((size_t)(dir << 7) + c) * (NT * NP) + j * NP;
    float rm = rmaxG[((dir << 7) + c) * NT + j];
    float m = rm + vm;
    float s = 0.f;
#pragma unroll
    for (int k = 0; k < NP; k += 4) {
      float4 p = *(const float4*)&row[k];
      s += ex2(p.x + V[k]     - m);
      s += ex2(p.y + V[k + 1] - m);
      s += ex2(p.z + V[k + 2] - m);
      s += ex2(p.w + V[k + 3] - m);
    }
    float nv = m + lg2(s);
    if (a) V[j] = nv;
    barrier_lds();
    float x = a ? nv : -3e38f;
    for (int off = 32; off; off >>= 1) x = fmaxf(x, __shfl_xor(x, off));
    vm = x;
    int cn = (dir == 0) ? (c + 1) : (c - 1);
    if (a) vIn[((size_t)(dir << 7) + cn) * NP + j] = nv;
  }
}

__global__ void k_crf_p3(const float* __restrict__ feats,
                         const float* __restrict__ trans,
                         const float* __restrict__ vIn,
                         float* __restrict__ wsA,
                         float* __restrict__ wsB){
  int dir = blockIdx.x >> 7;
  int c   = blockIdx.x & (CCH - 1);
  int lane = threadIdx.x;           // 64, single wave
  int t0 = c * SCH;
  bool a = (lane < NT);
  int j = a ? lane : 0;
  __shared__ float A[NP];
  __shared__ float U[NP];

  float trr[NT];
  float rm = -3e38f;
#pragma unroll
  for (int k = 0; k < NT; k++) {
    float vv = (dir == 0) ? trans[j * NT + k] : trans[k * NT + j];
    trr[k] = vv * F_L2E;
    rm = fmaxf(rm, trr[k]);
  }
  if (lane < NP) { A[lane] = -1e30f; U[lane] = -1e30f; }
  float v0 = vIn[((size_t)(dir << 7) + c) * NP + j];
  barrier_lds();
  if (a) A[j] = v0;
  barrier_lds();
  float am = a ? v0 : -3e38f;
  for (int off = 32; off; off >>= 1) am = fmaxf(am, __shfl_xor(am, off));

  if (dir == 0) {
    float fe = feats[(size_t)t0 * NT + j] * F_L2E;
    for (int s = 0; s < SCH; s++) {
      int t = t0 + s;
      int tn = (t + 1 < LSEQ) ? t + 1 : LSEQ - 1;
      float fe_n = feats[(size_t)tn * NT + j] * F_L2E;
      float m = rm + am;
      float ss = 0.f;
#pragma unroll
      for (int k = 0; k < NT; k++) ss += ex2(trr[k] + A[k] - m);
      float out = m + lg2(ss) + fe;
      if (a) wsA[(size_t)t * NT + j] = out * F_LN2;
      if (a) A[j] = out;
      barrier_lds();
      float x = a ? out : -3e38f;
      for (int off = 32; off; off >>= 1) x = fmaxf(x, __shfl_xor(x, off));
      am = x;
      fe = fe_n;
    }
  } else {
    float b = v0;                    // beta_{t+1}, per-lane register
    int tfirst = t0 + SCH; if (tfirst > LSEQ - 1) tfirst = LSEQ - 1;
    float fe = feats[(size_t)tfirst * NT + j] * F_L2E;   // feat_{t+1} for first step
    for (int s = 0; s < SCH; s++) {
      int t = t0 + SCH - 1 - s;
      float fe_n = feats[(size_t)t * NT + j] * F_L2E;    // next step's feat_{t+1}
      float out;
      if (t == LSEQ - 1) {
        out = b;                     // identity factor
      } else {
        if (a) U[j] = b + fe;
        barrier_lds();
        float um = a ? U[j] : -3e38f;
        for (int off = 32; off; off >>= 1) um = fmaxf(um, __shfl_xor(um, off));
        float m = rm + um;
        float ss = 0.f;
#pragma unroll
        for (int k = 0; k < NT; k++) ss += ex2(trr[k] + U[k] - m);
        out = m + lg2(ss);
        barrier_lds();
      }
      if (a) wsB[(size_t)t * NT + j] = out * F_LN2;
      b = out;
      fe = fe_n;
    }
  }
}

// ---------------------------------------------------------------------------
// Kernel: score = alpha + beta; tags = argmax.
// ---------------------------------------------------------------------------
__global__ void k_finish(const float* __restrict__ wsA, const float* __restrict__ wsB,
                         float* __restrict__ out){
  int t = blockIdx.x * 256 + threadIdx.x;
  float m = -3e38f; int bi = 0;
  for (int i = 0; i < NT; i++) {
    float sc = wsA[(size_t)t * NT + i] + wsB[(size_t)t * NT + i];
    out[(size_t)t * NT + i] = sc;
    if (sc > m) { m = sc; bi = i; }
  }
  out[(size_t)LSEQ * NT + t] = (float)bi;
}

// ---------------------------------------------------------------------------
extern "C" void kernel_launch(void* const* d_in, const int* in_sizes, int n_in,
                              void* d_out, int out_size, void* d_ws, size_t ws_size,
                              hipStream_t stream) {
  const int*   words  = (const int*)  d_in[0];
  const float* embed  = (const float*)d_in[1];
  const float* Wih_f  = (const float*)d_in[2];
  const float* Whh_f  = (const float*)d_in[3];
  const float* b_f    = (const float*)d_in[4];
  const float* Wih_b  = (const float*)d_in[5];
  const float* Whh_b  = (const float*)d_in[6];
  const float* b_b    = (const float*)d_in[7];
  const float* W_out  = (const float*)d_in[8];
  const float* b_out  = (const float*)d_in[9];
  const float* trans  = (const float*)d_in[10];
  float* out = (float*)d_out;

  float* wsf = (float*)d_ws;
  size_t off = 0;
  float* G_f   = wsf + off; off += (size_t)LSEQ * 1024;
  float* G_b   = wsf + off; off += (size_t)LSEQ * 1024;
  float* hf    = wsf + off; off += (size_t)LSEQ * 256;
  float* hb    = wsf + off; off += (size_t)LSEQ * 256;
  float* feats = wsf + off; off += (size_t)LSEQ * NT + 16;
  float* wsA   = wsf + off; off += (size_t)LSEQ * NT + 16;
  float* wsB   = wsf + off; off += (size_t)LSEQ * NT + 16;
  float* fac   = wsf + off; off += 2048;
  int*   Wq    = (int*)(wsf + off); off += 2 * 1024 * 64;
  // CRF scan scratch overlaps G_f (dead after k_lstm)
  float* Pg    = G_f;                                   // 256 * 34*36
  float* rmaxG = G_f + 256 * (NT * NP);                 // 256 * 34
  float* vIn   = rmaxG + 256 * NT + 32;                 // 256 * 36

  k_quant<<<2048, 64, 0, stream>>>(Whh_f, Whh_b, Wq, fac);
  k_gproj<<<dim3(512, 2), 256, 0, stream>>>(words, embed, Wih_f, b_f, Wih_b, b_b, G_f, G_b);
  k_lstm<<<2, 512, 0, stream>>>(Wq, fac, G_f, G_b, hf, hb);
  k_feats<<<512, 256, 0, stream>>>(hf, hb, W_out, b_out, feats);
  k_crf_p1<<<256, 320, 0, stream>>>(feats, trans, Pg, rmaxG);
  k_crf_p2<<<2, 64, 0, stream>>>(trans, Pg, rmaxG, vIn);
  k_crf_p3<<<256, 64, 0, stream>>>(feats, trans, vIn, wsA, wsB);
  k_finish<<<32, 256, 0, stream>>>(wsA, wsB, out);
}

// Round 6
// 8705.222 us; speedup vs baseline: 1.3314x; 1.0860x over previous
//
#include <hip/hip_runtime.h>
#include <cstdint>
#include <cstddef>

#define LSEQ 8192
#define NT   34
#define NP   36
#define SCH  64
#define CCH  128
#define F_L2E 1.4426950408889634f
#define F_LN2 0.6931471805599453f

typedef int v4i __attribute__((ext_vector_type(4)));

#if __has_builtin(__builtin_amdgcn_global_load_lds)
#define HAS_GLL 1
#else
#define HAS_GLL 0
#endif

__device__ __forceinline__ float ex2(float x){
#if __has_builtin(__builtin_amdgcn_exp2f)
  return __builtin_amdgcn_exp2f(x);
#else
  return exp2f(x);
#endif
}
__device__ __forceinline__ float lg2(float x){
#if __has_builtin(__builtin_amdgcn_logf)
  return __builtin_amdgcn_logf(x);   // v_log_f32 = log2
#else
  return __log2f(x);
#endif
}

__device__ __forceinline__ float sigf(float x){
  return __fdividef(1.f, 1.f + ex2(-F_L2E * x));
}
__device__ __forceinline__ float tanhf_fast(float x){
  return 1.f - __fdividef(2.f, ex2(2.f * F_L2E * x) + 1.f);
}

// int8 MFMA via inline asm: D==C tied ("+v"), A/B as 128-bit VGPR quads.
// asm (not builtin) for two reasons: (1) no builtin-signature risk,
// (2) "v" constraints FORCE arch-VGPR residency for the weight operands
// (R0/R2/R5 all showed the allocator parking 128 weight regs in AGPRs).
__device__ __forceinline__ v4i mfma_i8(v4i a, v4i b, v4i c){
  asm("v_mfma_i32_16x16x64_i8 %0, %1, %2, %0" : "+v"(c) : "v"(a), "v"(b));
  return c;
}

// barrier without the vmcnt(0) drain: LDS-only fence + s_barrier.
__device__ __forceinline__ void barrier_lds(){
  asm volatile("s_waitcnt lgkmcnt(0)\n\ts_barrier" ::: "memory");
}

// ---------------------------------------------------------------------------
// Kernel 1: quantize Whh (both dirs) to int8 with per-row scale.
// ---------------------------------------------------------------------------
__global__ void k_quant(const float* __restrict__ Whh_f,
                        const float* __restrict__ Whh_b,
                        int* __restrict__ Wq, float* __restrict__ fac){
  int bid = blockIdx.x;
  int dir = bid >> 10;
  int r   = bid & 1023;
  int i   = threadIdx.x;           // 0..63
  const float* W = (dir ? Whh_b : Whh_f) + r * 256 + i * 4;
  float w0 = W[0], w1 = W[1], w2 = W[2], w3 = W[3];
  float m = fmaxf(fmaxf(fabsf(w0), fabsf(w1)), fmaxf(fabsf(w2), fabsf(w3)));
  for (int s = 32; s; s >>= 1) m = fmaxf(m, __shfl_xor(m, s));
  float scale = (m > 0.f) ? m / 127.f : 1.f;
  float inv = __fdividef(1.f, scale);
  int q0 = (int)rintf(w0 * inv), q1 = (int)rintf(w1 * inv);
  int q2 = (int)rintf(w2 * inv), q3 = (int)rintf(w3 * inv);
  q0 = max(-127, min(127, q0)); q1 = max(-127, min(127, q1));
  q2 = max(-127, min(127, q2)); q3 = max(-127, min(127, q3));
  int p = (q0 & 255) | ((q1 & 255) << 8) | ((q2 & 255) << 16) | ((q3 & 255) << 24);
  Wq[(dir << 16) + (r << 6) + i] = p;
  if (i == 0) fac[(dir << 10) + r] = scale * (1.f / 127.f);
}

// ---------------------------------------------------------------------------
// Kernel 2: G[t][u*4+gate] = b[r] + sum_e embed[words[t]][e] * Wih[r][e]
// (gate-interleaved output layout so k_lstm reads one float4 per unit)
// ---------------------------------------------------------------------------
__global__ void k_gproj(const int* __restrict__ words,
                        const float* __restrict__ embed,
                        const float* __restrict__ Wih_f, const float* __restrict__ b_f,
                        const float* __restrict__ Wih_b, const float* __restrict__ b_b,
                        float* __restrict__ G_f, float* __restrict__ G_b){
  int dir = blockIdx.y;
  const float* Wih = dir ? Wih_b : Wih_f;
  const float* bb  = dir ? b_b  : b_f;
  float* G = dir ? G_b : G_f;
  int t0 = blockIdx.x * 16;
  __shared__ __align__(16) float X[16 * 256];
  for (int idx = threadIdx.x; idx < 16 * 256; idx += 256) {
    int tt = idx >> 8, e = idx & 255;
    X[idx] = embed[(size_t)words[t0 + tt] * 256 + e];
  }
  __syncthreads();
  const float4* X4 = (const float4*)X;
  for (int rb = 0; rb < 4; rb++) {
    int r = rb * 256 + threadIdx.x;      // gate rb, unit threadIdx.x
    float bv = bb[r];
    float acc[16];
#pragma unroll
    for (int tt = 0; tt < 16; tt++) acc[tt] = bv;
    const float4* W4 = (const float4*)(Wih + (size_t)r * 256);
    for (int eb = 0; eb < 64; eb++) {
      float4 w = W4[eb];
#pragma unroll
      for (int tt = 0; tt < 16; tt++) {
        float4 x = X4[tt * 64 + eb];
        acc[tt] += w.x * x.x + w.y * x.y + w.z * x.z + w.w * x.w;
      }
    }
    for (int tt = 0; tt < 16; tt++)
      G[(size_t)(t0 + tt) * 1024 + (threadIdx.x << 2) + rb] = acc[tt];
  }
}

// ---------------------------------------------------------------------------
// Kernel 3: LSTM recurrences. block 0 = forward, block 1 = backward.
// MFMA version: the per-step 1024x256 int8 matvec runs on the MATRIX pipe
// (v_mfma_i32_16x16x64_i8, 32 per wave = 256/step, C-chained over 4 K-slices)
// instead of the VALU, whose measured ~4-6 cyc/dot4 issue rate pinned every
// dot-based variant at ~2450 cyc/step (R0/R2/R5 invariance).
// Mapping: wave w owns units [32w,32w+32). A-tile (g,h): rows g*256+w*32+h*16
// +(lane&15); lane also indexes K-chunk via lane>>4. B = h broadcast into all
// 16 cols: one ds_read_b128 per K-slice, address shared by 16 lanes. A and B
// use the SAME slot->k convention, so the contraction is correct for any true
// HW k-mapping (bijection argument); D layout (col=lane&15, row=(lane>>4)*4+r)
// is the HW-verified dtype-independent one. After MFMA, lane (lane&15)==0
// writes its 4 consecutive units' raw sums per (g,h) -> graw[4KB]; barrier;
// 256 threads do gates (int32 sums exact -> bit-identical to dot4 version).
// G staged in 4-step chunks (2x16KB) via global_load_lds, one vmcnt(0) drain
// per 4 steps (R5's proven staging, gate-interleaved G).
// ---------------------------------------------------------------------------
__global__ __launch_bounds__(512, 2) void k_lstm(const int* __restrict__ Wq,
                                                 const float* __restrict__ fac,
                                                 const float* __restrict__ G_f,
                                                 const float* __restrict__ G_b,
                                                 float* __restrict__ hf,
                                                 float* __restrict__ hb){
  int dir = blockIdx.x;
  const int* Wqd = Wq + (dir << 16);
  const float* facp = fac + (dir << 10);
  const float* G = dir ? G_b : G_f;
  float* hout = dir ? hb : hf;
  int tid = threadIdx.x;
  int ln  = tid & 63;            // lane
  int wv  = tid >> 6;            // wave 0..7
  int lg  = ln >> 4;             // 16-lane group 0..3 (K-chunk / D row-group)
  int lr  = ln & 15;             // A row / D col within tile

  __shared__ __align__(16) float GL[2][4 * 1024];   // 2 x 16KB G staging
  __shared__ __align__(16) int h8c[2][64];          // 2 x 256 int8 h
  __shared__ __align__(16) int graw[1024];          // raw int32 gate sums

  // A operands: 8 tiles (gate g, half h) x 4 K-slices; 128 VGPRs total.
  // wgt[g][h][ks] = W[row R] bytes [ks*64 + lg*16 .. +15], R = g*256+wv*32+h*16+lr
  v4i wgt[4][2][4];
#pragma unroll
  for (int g = 0; g < 4; g++)
#pragma unroll
    for (int h = 0; h < 2; h++) {
      int R = g * 256 + wv * 32 + h * 16 + lr;
#pragma unroll
      for (int ks = 0; ks < 4; ks++)
        wgt[g][h][ks] = *(const v4i*)(Wqd + R * 64 + ks * 16 + lg * 4);
    }

  float fI = 0.f, fF = 0.f, fG = 0.f, fO = 0.f;
  if (tid < 256) {
    fI = facp[tid]; fF = facp[tid + 256];
    fG = facp[tid + 512]; fO = facp[tid + 768];
  }
  if (tid < 64) h8c[0][tid] = 0;
  float c = 0.f;
  v4i zero = {0, 0, 0, 0};

  // stage chunk cn (4 timesteps = 16KB contiguous) into GL[cn&1].
  auto stage = [&](int cn) {
    int half = cn & 1;
    int gt0 = dir ? (8191 - (cn * 4 + 3)) : (cn * 4);
    const char* src = (const char*)(G + (size_t)gt0 * 1024) + (wv << 11) + (ln << 4);
    char* dst = (char*)&GL[half][0] + (wv << 11);
#pragma unroll
    for (int i = 0; i < 2; i++) {
#if HAS_GLL
      __builtin_amdgcn_global_load_lds(
          (const __attribute__((address_space(1))) unsigned int*)(src + (i << 10)),
          (__attribute__((address_space(3))) unsigned int*)(dst + (i << 10)),
          16, 0, 0);
#else
      *(float4*)(dst + (i << 10) + (ln << 4)) = *(const float4*)(src + (i << 10));
#endif
    }
  };

  // Phase A (all 8 waves): matvec on the matrix pipe, scatter raw sums to graw.
  auto stepA = [&](const int* hbuf) {
    const v4i* hb4 = (const v4i*)hbuf;     // B: h bytes [ks*64+lg*16..+15]
    v4i b0 = hb4[lg], b1 = hb4[4 + lg], b2 = hb4[8 + lg], b3 = hb4[12 + lg];
#pragma unroll
    for (int g = 0; g < 4; g++)
#pragma unroll
      for (int h = 0; h < 2; h++) {
        v4i a = mfma_i8(wgt[g][h][0], b0, zero);
        a = mfma_i8(wgt[g][h][1], b1, a);
        a = mfma_i8(wgt[g][h][2], b2, a);
        a = mfma_i8(wgt[g][h][3], b3, a);
        if (lr == 0)   // col-0 lanes: 4 consecutive units' gate-g raw sums
          *(v4i*)&graw[g * 256 + wv * 32 + h * 16 + lg * 4] = a;
      }
  };

  // prologue: stage chunk 0, drain, sync
  stage(0);
  asm volatile("s_waitcnt vmcnt(0)" ::: "memory");
  __syncthreads();

  int cur = 0;
  for (int cn = 0; cn < 2048; ++cn) {
    if (cn + 1 < 2048) stage(cn + 1);       // writes the OTHER half; WAR-safe
    const float* Hc = GL[cn & 1];
#pragma unroll
    for (int s = 0; s < 4; ++s) {
      int row = dir ? (3 - s) : s;
      int t = (cn << 2) + s;
      stepA(h8c[cur]);
      barrier_lds();                        // graw ready
      if (tid < 256) {
        int u = tid;
        int aI = graw[u], aF = graw[256 + u], aG = graw[512 + u], aO = graw[768 + u];
        float4 gv = ((const float4*)(Hc + (row << 10)))[u];
        float ri = (float)aI * fI + gv.x;
        float rf = (float)aF * fF + gv.y;
        float rg = (float)aG * fG + gv.z;
        float ro = (float)aO * fO + gv.w;
        float is = sigf(ri), fs = sigf(rf);
        float gt = tanhf_fast(rg), os = sigf(ro);
        c = fs * c + is * gt;
        float hv = os * tanhf_fast(c);
        int time = dir ? (8191 - t) : t;
        hout[(size_t)time * 256 + u] = hv;   // queues; drained at chunk end
        ((signed char*)h8c[cur ^ 1])[u] = (signed char)(int)rintf(hv * 127.f);
      }
      cur ^= 1;
      if (s == 3) {
        // chunk boundary: drain staging once per 4 steps (~latency well covered)
        asm volatile("s_waitcnt vmcnt(0) lgkmcnt(0)\n\ts_barrier" ::: "memory");
      } else {
        barrier_lds();
      }
    }
  }
}

// ---------------------------------------------------------------------------
// Kernel 4: feats = [hf | hb] @ W_out.T + b_out.
// ---------------------------------------------------------------------------
__global__ void k_feats(const float* __restrict__ hf, const float* __restrict__ hb,
                        const float* __restrict__ W_out, const float* __restrict__ b_out,
                        float* __restrict__ feats){
  int t0 = blockIdx.x * 16;
  for (int oi = threadIdx.x; oi < 16 * NT; oi += 256) {
    int tt = oi / NT;
    int tag = oi - tt * NT;
    int t = t0 + tt;
    const float4* w4 = (const float4*)(W_out + (size_t)tag * 512);
    const float4* a4 = (const float4*)(hf + (size_t)t * 256);
    const float4* c4 = (const float4*)(hb + (size_t)t * 256);
    float acc = b_out[tag];
    for (int k = 0; k < 64; k++) {
      float4 w = w4[k]; float4 h = a4[k];
      acc += w.x * h.x + w.y * h.y + w.z * h.z + w.w * h.w;
    }
    for (int k = 0; k < 64; k++) {
      float4 w = w4[64 + k]; float4 h = c4[k];
      acc += w.x * h.x + w.y * h.y + w.z * h.z + w.w * h.w;
    }
    feats[(size_t)t * NT + tag] = acc;
  }
}

// ---------------------------------------------------------------------------
// CRF as a chunked associative scan in the (lse,+) semiring, log2-domain.
// alpha: M_t[j][i] = λ(tr[j][i] + feat_t[j]);  alpha_t = M_t ⊗ alpha_{t-1}
// beta : N_t[j][i] = λ(tr[i][j] + feat_{t+1}[i]); beta_t = N_t ⊗ beta_{t+1},
//        N_{L-1} = identity, virtual beta_L[j] = lse_i λ tr[i][j].
// Phase 1: per-chunk matrix products (128 chunks x 2 dirs, parallel).
// Phase 2: sequential matvec prefix over 128 chunk products (2 blocks).
// Phase 3: per-chunk vector re-scan emitting wsA/wsB (parallel).
// ---------------------------------------------------------------------------
__global__ __launch_bounds__(320) void k_crf_p1(const float* __restrict__ feats,
                                                const float* __restrict__ trans,
                                                float* __restrict__ Pg,
                                                float* __restrict__ rmaxG){
  int dir = blockIdx.x >> 7;
  int c   = blockIdx.x & (CCH - 1);
  int tid = threadIdx.x;
  int t0  = c * SCH;

  __shared__ __align__(16) float TRM[NT * NP];
  __shared__ float Fe[(SCH + 1) * NT];
  __shared__ __align__(16) float Pbuf[2][NT * NP];
  __shared__ float CM[NP];
  __shared__ float RMs[NT];

  for (int idx = tid; idx < NT * NT; idx += 320) {
    int j = idx / NT, k = idx - j * NT;
    float v = (dir == 0) ? trans[j * NT + k] : trans[k * NT + j];
    TRM[j * NP + k] = v * F_L2E;
  }
  for (int idx = tid; idx < (SCH + 1) * NT; idx += 320) {
    int s = idx / NT, j = idx - s * NT;
    int t = t0 + s; if (t > LSEQ - 1) t = LSEQ - 1;
    Fe[idx] = feats[(size_t)t * NT + j] * F_L2E;
  }
  for (int idx = tid; idx < NT * NP; idx += 320) {
    int k = idx / NP, i = idx - k * NP;
    Pbuf[0][idx] = (i < NT && i == k) ? 0.f : -1e30f;
  }
  if (tid < NP) CM[tid] = (tid < NT) ? 0.f : -1e30f;
  __syncthreads();
  if (tid < NT) {
    float m = -3e38f;
    for (int k = 0; k < NT; k++) m = fmaxf(m, TRM[tid * NP + k]);
    RMs[tid] = m;
  }
  __syncthreads();
  for (int idx = tid; idx < NT * NT; idx += 320) {
    int j = idx / NT, k = idx - j * NT;
    TRM[j * NP + k] -= RMs[j];
  }
  __syncthreads();

  int cur = 0;
  int j = tid / 9, g = tid - (tid / 9) * 9;
  bool act = (tid < 306);
  int i0 = 4 * g;

  for (int s = 0; s < SCH; s++) {
    int t = (dir == 0) ? (t0 + s) : (t0 + SCH - 1 - s);
    if (dir == 1 && t == LSEQ - 1) continue;   // identity factor at t=L-1
    const float* Pc = Pbuf[cur];
    float* Pn = Pbuf[cur ^ 1];
    if (act) {
      float cm0 = CM[i0], cm1 = CM[i0 + 1], cm2 = CM[i0 + 2], cm3 = CM[i0 + 3];
      float s0 = 0, s1 = 0, s2 = 0, s3 = 0;
      const float* trp = TRM + j * NP;
      const float* fep = Fe + (t + 1 - t0) * NT;   // only read when dir==1
#pragma unroll
      for (int k = 0; k < NT; k++) {
        float trv = trp[k];
        if (dir == 1) trv += fep[k];
        float4 p = *(const float4*)&Pc[k * NP + i0];
        s0 += ex2(trv + p.x - cm0);
        s1 += ex2(trv + p.y - cm1);
        s2 += ex2(trv + p.z - cm2);
        s3 += ex2(trv + p.w - cm3);
      }
      float base = RMs[j] + ((dir == 0) ? Fe[(t - t0) * NT + j] : 0.f);
      float4 o;
      o.x = base + cm0 + lg2(s0);
      o.y = base + cm1 + lg2(s1);
      o.z = (i0 + 2 < NT) ? (base + cm2 + lg2(s2)) : -1e30f;
      o.w = (i0 + 3 < NT) ? (base + cm3 + lg2(s3)) : -1e30f;
      *(float4*)&Pn[j * NP + i0] = o;
    }
    __syncthreads();
    if (tid < NP) {
      float m = -3e38f;
      const float* col = Pn + tid;
      for (int k = 0; k < NT; k++) m = fmaxf(m, col[k * NP]);
      CM[tid] = m;
    }
    cur ^= 1;
    __syncthreads();
  }

  const float* Pf = Pbuf[cur];
  size_t base = (size_t)((dir << 7) + c) * (NT * NP);
  for (int idx = tid; idx < NT * NP; idx += 320)
    Pg[base + idx] = Pf[idx];
  if (tid < NT) {
    float m = -3e38f;
    for (int i = 0; i < NT; i++) m = fmaxf(m, Pf[tid * NP + i]);
    rmaxG[((dir << 7) + c) * NT + tid] = m;
  }
}

__global__ void k_crf_p2(const float* __restrict__ trans,
                         const float* __restrict__ Pg,
                         const float* __restrict__ rmaxG,
                         float* __restrict__ vIn){
  int dir = blockIdx.x;
  int lane = threadIdx.x;           // 64, single wave
  bool a = (lane < NT);
  int j = a ? lane : 0;
  __shared__ float V[NP];

  float v;
  if (dir == 0) {
    v = (lane == 32) ? 0.f : -10000.f * F_L2E;
  } else {
    float m = -3e38f;
    for (int i = 0; i < NT; i++) m = fmaxf(m, trans[i * NT + j]);
    float s = 0.f;
    for (int i = 0; i < NT; i++) s += ex2((trans[i * NT + j] - m) * F_L2E);
    v = m * F_L2E + lg2(s);
  }
  if (lane < NP) V[lane] = -1e30f;
  barrier_lds();
  if (a) V[j] = v;
  barrier_lds();
  float vm = a ? v : -3e38f;
  for (int off = 32; off; off >>= 1) vm = fmaxf(vm, __shfl_xor(vm, off));

  if (a) {
    int c0 = (dir == 0) ? 0 : (CCH - 1);
    vIn[((size_t)(dir << 7) + c0) * NP + j] = v;
  }

  for (int it = 0; it < CCH - 1; it++) {
    int c = (dir == 0) ? it : (CCH - 1 - it);
    const float* row = Pg + ((size_t)(dir << 7) + c) * (NT * NP) + j * NP;
    float rm = rmaxG[((dir << 7) + c) * NT + j];
    float m = rm + vm;
    float s = 0.f;
#pragma unroll
    for (int k = 0; k < NP; k += 4) {
      float4 p = *(const float4*)&row[k];
      s += ex2(p.x + V[k]     - m);
      s += ex2(p.y + V[k + 1] - m);
      s += ex2(p.z + V[k + 2] - m);
      s += ex2(p.w + V[k + 3] - m);
    }
    float nv = m + lg2(s);
    if (a) V[j] = nv;
    barrier_lds();
    float x = a ? nv : -3e38f;
    for (int off = 32; off; off >>= 1) x = fmaxf(x, __shfl_xor(x, off));
    vm = x;
    int cn = (dir == 0) ? (c + 1) : (c - 1);
    if (a) vIn[((size_t)(dir << 7) + cn) * NP + j] = nv;
  }
}

__global__ void k_crf_p3(const float* __restrict__ feats,
                         const float* __restrict__ trans,
                         const float* __restrict__ vIn,
                         float* __restrict__ wsA,
                         float* __restrict__ wsB){
  int dir = blockIdx.x >> 7;
  int c   = blockIdx.x & (CCH - 1);
  int lane = threadIdx.x;           // 64, single wave
  int t0 = c * SCH;
  bool a = (lane < NT);
  int j = a ? lane : 0;
  __shared__ float A[NP];
  __shared__ float U[NP];

  float trr[NT];
  float rm = -3e38f;
#pragma unroll
  for (int k = 0; k < NT; k++) {
    float vv = (dir == 0) ? trans[j * NT + k] : trans[k * NT + j];
    trr[k] = vv * F_L2E;
    rm = fmaxf(rm, trr[k]);
  }
  if (lane < NP) { A[lane] = -1e30f; U[lane] = -1e30f; }
  float v0 = vIn[((size_t)(dir << 7) + c) * NP + j];
  barrier_lds();
  if (a) A[j] = v0;
  barrier_lds();
  float am = a ? v0 : -3e38f;
  for (int off = 32; off; off >>= 1) am = fmaxf(am, __shfl_xor(am, off));

  if (dir == 0) {
    float fe = feats[(size_t)t0 * NT + j] * F_L2E;
    for (int s = 0; s < SCH; s++) {
      int t = t0 + s;
      int tn = (t + 1 < LSEQ) ? t + 1 : LSEQ - 1;
      float fe_n = feats[(size_t)tn * NT + j] * F_L2E;
      float m = rm + am;
      float ss = 0.f;
#pragma unroll
      for (int k = 0; k < NT; k++) ss += ex2(trr[k] + A[k] - m);
      float out = m + lg2(ss) + fe;
      if (a) wsA[(size_t)t * NT + j] = out * F_LN2;
      if (a) A[j] = out;
      barrier_lds();
      float x = a ? out : -3e38f;
      for (int off = 32; off; off >>= 1) x = fmaxf(x, __shfl_xor(x, off));
      am = x;
      fe = fe_n;
    }
  } else {
    float b = v0;                    // beta_{t+1}, per-lane register
    int tfirst = t0 + SCH; if (tfirst > LSEQ - 1) tfirst = LSEQ - 1;
    float fe = feats[(size_t)tfirst * NT + j] * F_L2E;   // feat_{t+1} for first step
    for (int s = 0; s < SCH; s++) {
      int t = t0 + SCH - 1 - s;
      float fe_n = feats[(size_t)t * NT + j] * F_L2E;    // next step's feat_{t+1}
      float out;
      if (t == LSEQ - 1) {
        out = b;                     // identity factor
      } else {
        if (a) U[j] = b + fe;
        barrier_lds();
        float um = a ? U[j] : -3e38f;
        for (int off = 32; off; off >>= 1) um = fmaxf(um, __shfl_xor(um, off));
        float m = rm + um;
        float ss = 0.f;
#pragma unroll
        for (int k = 0; k < NT; k++) ss += ex2(trr[k] + U[k] - m);
        out = m + lg2(ss);
        barrier_lds();
      }
      if (a) wsB[(size_t)t * NT + j] = out * F_LN2;
      b = out;
      fe = fe_n;
    }
  }
}

// ---------------------------------------------------------------------------
// Kernel: score = alpha + beta; tags = argmax.
// ---------------------------------------------------------------------------
__global__ void k_finish(const float* __restrict__ wsA, const float* __restrict__ wsB,
                         float* __restrict__ out){
  int t = blockIdx.x * 256 + threadIdx.x;
  float m = -3e38f; int bi = 0;
  for (int i = 0; i < NT; i++) {
    float sc = wsA[(size_t)t * NT + i] + wsB[(size_t)t * NT + i];
    out[(size_t)t * NT + i] = sc;
    if (sc > m) { m = sc; bi = i; }
  }
  out[(size_t)LSEQ * NT + t] = (float)bi;
}

// ---------------------------------------------------------------------------
extern "C" void kernel_launch(void* const* d_in, const int* in_sizes, int n_in,
                              void* d_out, int out_size, void* d_ws, size_t ws_size,
                              hipStream_t stream) {
  const int*   words  = (const int*)  d_in[0];
  const float* embed  = (const float*)d_in[1];
  const float* Wih_f  = (const float*)d_in[2];
  const float* Whh_f  = (const float*)d_in[3];
  const float* b_f    = (const float*)d_in[4];
  const float* Wih_b  = (const float*)d_in[5];
  const float* Whh_b  = (const float*)d_in[6];
  const float* b_b    = (const float*)d_in[7];
  const float* W_out  = (const float*)d_in[8];
  const float* b_out  = (const float*)d_in[9];
  const float* trans  = (const float*)d_in[10];
  float* out = (float*)d_out;

  float* wsf = (float*)d_ws;
  size_t off = 0;
  float* G_f   = wsf + off; off += (size_t)LSEQ * 1024;
  float* G_b   = wsf + off; off += (size_t)LSEQ * 1024;
  float* hf    = wsf + off; off += (size_t)LSEQ * 256;
  float* hb    = wsf + off; off += (size_t)LSEQ * 256;
  float* feats = wsf + off; off += (size_t)LSEQ * NT + 16;
  float* wsA   = wsf + off; off += (size_t)LSEQ * NT + 16;
  float* wsB   = wsf + off; off += (size_t)LSEQ * NT + 16;
  float* fac   = wsf + off; off += 2048;
  int*   Wq    = (int*)(wsf + off); off += 2 * 1024 * 64;
  // CRF scan scratch overlaps G_f (dead after k_lstm)
  float* Pg    = G_f;                                   // 256 * 34*36
  float* rmaxG = G_f + 256 * (NT * NP);                 // 256 * 34
  float* vIn   = rmaxG + 256 * NT + 32;                 // 256 * 36

  k_quant<<<2048, 64, 0, stream>>>(Whh_f, Whh_b, Wq, fac);
  k_gproj<<<dim3(512, 2), 256, 0, stream>>>(words, embed, Wih_f, b_f, Wih_b, b_b, G_f, G_b);
  k_lstm<<<2, 512, 0, stream>>>(Wq, fac, G_f, G_b, hf, hb);
  k_feats<<<512, 256, 0, stream>>>(hf, hb, W_out, b_out, feats);
  k_crf_p1<<<256, 320, 0, stream>>>(feats, trans, Pg, rmaxG);
  k_crf_p2<<<2, 64, 0, stream>>>(trans, Pg, rmaxG, vIn);
  k_crf_p3<<<256, 64, 0, stream>>>(feats, trans, vIn, wsA, wsB);
  k_finish<<<32, 256, 0, stream>>>(wsA, wsB, out);
}

// Round 7
// 8388.981 us; speedup vs baseline: 1.3816x; 1.0377x over previous
//
#include <hip/hip_runtime.h>
#include <cstdint>
#include <cstddef>

#define LSEQ 8192
#define NT   34
#define NP   36
#define SCH  64
#define CCH  128
#define F_L2E 1.4426950408889634f
#define F_LN2 0.6931471805599453f

typedef int v4i __attribute__((ext_vector_type(4)));

#if __has_builtin(__builtin_amdgcn_global_load_lds)
#define HAS_GLL 1
#else
#define HAS_GLL 0
#endif

// int8 MFMA. Builtin REQUIRED for correctness: the compiler inserts the
// mandatory MFMA->VALU/DS hazard wait-states (s_nop). R6 used raw inline asm;
// the hazard recognizer cannot see into asm, the accumulator was read back
// before the MFMA retired, and the output was stale -> absmax 19.
#if __has_builtin(__builtin_amdgcn_mfma_i32_16x16x64_i8)
#define MFMA_I8(a,b,c) __builtin_amdgcn_mfma_i32_16x16x64_i8((a),(b),(c),0,0,0)
#else
__device__ __forceinline__ v4i mfma_i8_asm(v4i a, v4i b, v4i c){
  asm volatile("v_mfma_i32_16x16x64_i8 %0, %1, %2, %0\n\ts_nop 7\n\ts_nop 7"
               : "+v"(c) : "v"(a), "v"(b));
  return c;
}
#define MFMA_I8(a,b,c) mfma_i8_asm((a),(b),(c))
#endif

__device__ __forceinline__ float ex2(float x){
#if __has_builtin(__builtin_amdgcn_exp2f)
  return __builtin_amdgcn_exp2f(x);
#else
  return exp2f(x);
#endif
}
__device__ __forceinline__ float lg2(float x){
#if __has_builtin(__builtin_amdgcn_logf)
  return __builtin_amdgcn_logf(x);   // v_log_f32 = log2
#else
  return __log2f(x);
#endif
}

__device__ __forceinline__ float sigf(float x){
  return __fdividef(1.f, 1.f + ex2(-F_L2E * x));
}
__device__ __forceinline__ float tanhf_fast(float x){
  return 1.f - __fdividef(2.f, ex2(2.f * F_L2E * x) + 1.f);
}

// barrier without the vmcnt(0) drain: LDS-only fence + s_barrier.
__device__ __forceinline__ void barrier_lds(){
  asm volatile("s_waitcnt lgkmcnt(0)\n\ts_barrier" ::: "memory");
}

// ---------------------------------------------------------------------------
// Kernel 1: quantize Whh (both dirs) to int8 with per-row scale.
// ---------------------------------------------------------------------------
__global__ void k_quant(const float* __restrict__ Whh_f,
                        const float* __restrict__ Whh_b,
                        int* __restrict__ Wq, float* __restrict__ fac){
  int bid = blockIdx.x;
  int dir = bid >> 10;
  int r   = bid & 1023;
  int i   = threadIdx.x;           // 0..63
  const float* W = (dir ? Whh_b : Whh_f) + r * 256 + i * 4;
  float w0 = W[0], w1 = W[1], w2 = W[2], w3 = W[3];
  float m = fmaxf(fmaxf(fabsf(w0), fabsf(w1)), fmaxf(fabsf(w2), fabsf(w3)));
  for (int s = 32; s; s >>= 1) m = fmaxf(m, __shfl_xor(m, s));
  float scale = (m > 0.f) ? m / 127.f : 1.f;
  float inv = __fdividef(1.f, scale);
  int q0 = (int)rintf(w0 * inv), q1 = (int)rintf(w1 * inv);
  int q2 = (int)rintf(w2 * inv), q3 = (int)rintf(w3 * inv);
  q0 = max(-127, min(127, q0)); q1 = max(-127, min(127, q1));
  q2 = max(-127, min(127, q2)); q3 = max(-127, min(127, q3));
  int p = (q0 & 255) | ((q1 & 255) << 8) | ((q2 & 255) << 16) | ((q3 & 255) << 24);
  Wq[(dir << 16) + (r << 6) + i] = p;
  if (i == 0) fac[(dir << 10) + r] = scale * (1.f / 127.f);
}

// ---------------------------------------------------------------------------
// Kernel 2: G[t][u*4+gate] = b[r] + sum_e embed[words[t]][e] * Wih[r][e]
// (gate-interleaved output layout so k_lstm reads one float4 per unit;
//  verified correct in R5, absmax 0)
// ---------------------------------------------------------------------------
__global__ void k_gproj(const int* __restrict__ words,
                        const float* __restrict__ embed,
                        const float* __restrict__ Wih_f, const float* __restrict__ b_f,
                        const float* __restrict__ Wih_b, const float* __restrict__ b_b,
                        float* __restrict__ G_f, float* __restrict__ G_b){
  int dir = blockIdx.y;
  const float* Wih = dir ? Wih_b : Wih_f;
  const float* bb  = dir ? b_b  : b_f;
  float* G = dir ? G_b : G_f;
  int t0 = blockIdx.x * 16;
  __shared__ __align__(16) float X[16 * 256];
  for (int idx = threadIdx.x; idx < 16 * 256; idx += 256) {
    int tt = idx >> 8, e = idx & 255;
    X[idx] = embed[(size_t)words[t0 + tt] * 256 + e];
  }
  __syncthreads();
  const float4* X4 = (const float4*)X;
  for (int rb = 0; rb < 4; rb++) {
    int r = rb * 256 + threadIdx.x;      // gate rb, unit threadIdx.x
    float bv = bb[r];
    float acc[16];
#pragma unroll
    for (int tt = 0; tt < 16; tt++) acc[tt] = bv;
    const float4* W4 = (const float4*)(Wih + (size_t)r * 256);
    for (int eb = 0; eb < 64; eb++) {
      float4 w = W4[eb];
#pragma unroll
      for (int tt = 0; tt < 16; tt++) {
        float4 x = X4[tt * 64 + eb];
        acc[tt] += w.x * x.x + w.y * x.y + w.z * x.z + w.w * x.w;
      }
    }
    for (int tt = 0; tt < 16; tt++)
      G[(size_t)(t0 + tt) * 1024 + (threadIdx.x << 2) + rb] = acc[tt];
  }
}

// ---------------------------------------------------------------------------
// Kernel 3: LSTM recurrences. block 0 = forward, block 1 = backward.
// MFMA matvec with NO extraction round-trip: because B's 16 columns all carry
// the same h vector, D's columns are identical -- EVERY lane of 16-group lg
// holds the full gate sums of units 32w + h*16 + lg*4 + reg (all 4 gates, its
// 8 tiles) in registers. Lane lr statically selects (h=lr>>2&1, r=lr&3) via
// cndmask chains and runs the gate nonlinearity for ONE unit; 32 lanes/wave
// x 8 waves cover all 256 units in parallel. h8 repacked via DPP quad-add
// (R5-proven) + one ds_write_b32/wave. ONE barrier per step.
// A-fragment: row=lane&15, k=16*(lane>>4)+byte-order elem; D: row=(lane>>4)*4
// +reg (col irrelevant, all equal) -- HW-verified dtype-independent mapping.
// G staged in 4-step chunks (2x16KB) via global_load_lds, one vmcnt(0) per
// chunk (R5's verified staging). int32 sums exact -> bit-identical h path.
// ---------------------------------------------------------------------------
__global__ __launch_bounds__(512, 2) void k_lstm(const int* __restrict__ Wq,
                                                 const float* __restrict__ fac,
                                                 const float* __restrict__ G_f,
                                                 const float* __restrict__ G_b,
                                                 float* __restrict__ hf,
                                                 float* __restrict__ hb){
  int dir = blockIdx.x;
  const int* Wqd = Wq + (dir << 16);
  const float* facp = fac + (dir << 10);
  const float* G = dir ? G_b : G_f;
  float* hout = dir ? hb : hf;
  int tid = threadIdx.x;
  int ln  = tid & 63;            // lane
  int wv  = tid >> 6;            // wave 0..7
  int lg  = ln >> 4;             // 16-lane group = K-chunk = D row-group
  int lr  = ln & 15;             // A row within tile
  int h_l = (lr >> 2) & 1;       // this lane's half-tile (lanes 8..15 mirror 0..7)
  int r_l = lr & 3;              // this lane's reg index within D row-group
  int u   = (wv << 5) + (h_l << 4) + (lg << 2) + r_l;   // unit this lane owns

  __shared__ __align__(16) float GL[2][4 * 1024];   // 2 x 16KB G staging
  __shared__ __align__(16) int h8c[2][64];          // 2 x 256 int8 h

  // A operands: 8 tiles (gate g, half h) x 4 K-slices; 128 regs (VGPR or AGPR
  // -- both are native MFMA sources on gfx950's unified file).
  v4i wgt[4][2][4];
#pragma unroll
  for (int g = 0; g < 4; g++)
#pragma unroll
    for (int h = 0; h < 2; h++) {
      int R = g * 256 + (wv << 5) + (h << 4) + lr;
#pragma unroll
      for (int ks = 0; ks < 4; ks++)
        wgt[g][h][ks] = *(const v4i*)(Wqd + R * 64 + ks * 16 + lg * 4);
    }

  float fI = facp[u], fF = facp[u + 256], fG = facp[u + 512], fO = facp[u + 768];
  if (tid < 64) h8c[0][tid] = 0;
  float c = 0.f;
  v4i zero = {0, 0, 0, 0};

  // stage chunk cn (4 timesteps = 16KB contiguous) into GL[cn&1].
  auto stage = [&](int cn) {
    int half = cn & 1;
    int gt0 = dir ? (8191 - (cn * 4 + 3)) : (cn * 4);
    const char* src = (const char*)(G + (size_t)gt0 * 1024) + (wv << 11) + (ln << 4);
    char* dst = (char*)&GL[half][0] + (wv << 11);
#pragma unroll
    for (int i = 0; i < 2; i++) {
#if HAS_GLL
      __builtin_amdgcn_global_load_lds(
          (const __attribute__((address_space(1))) unsigned int*)(src + (i << 10)),
          (__attribute__((address_space(3))) unsigned int*)(dst + (i << 10)),
          16, 0, 0);
#else
      *(float4*)(dst + (i << 10) + (ln << 4)) = *(const float4*)(src + (i << 10));
#endif
    }
  };

  auto step = [&](int t, const float* Grow, const int* bufR, int* bufW) {
    // B operand: h bytes [ks*64 + lg*16 .. +15]; 16-lane shared addr = broadcast
    const v4i* hb4 = (const v4i*)bufR;
    v4i b0 = hb4[lg], b1 = hb4[4 + lg], b2 = hb4[8 + lg], b3 = hb4[12 + lg];
    float4 gv = ((const float4*)Grow)[u];   // issued early, overlaps MFMA
    v4i res[4][2];
#pragma unroll
    for (int g = 0; g < 4; g++)
#pragma unroll
      for (int h = 0; h < 2; h++) {
        v4i a = MFMA_I8(wgt[g][h][0], b0, zero);
        a = MFMA_I8(wgt[g][h][1], b1, a);
        a = MFMA_I8(wgt[g][h][2], b2, a);
        a = MFMA_I8(wgt[g][h][3], b3, a);
        res[g][h] = a;
      }
    // static cndmask selection of this lane's unit from its 8 tiles
    bool sh = h_l != 0;
    bool s1 = (r_l & 1) != 0;
    bool s2 = (r_l & 2) != 0;
    v4i tI = sh ? res[0][1] : res[0][0];
    v4i tF = sh ? res[1][1] : res[1][0];
    v4i tG = sh ? res[2][1] : res[2][0];
    v4i tO = sh ? res[3][1] : res[3][0];
    int vI = s2 ? (s1 ? tI.w : tI.z) : (s1 ? tI.y : tI.x);
    int vF = s2 ? (s1 ? tF.w : tF.z) : (s1 ? tF.y : tF.x);
    int vG = s2 ? (s1 ? tG.w : tG.z) : (s1 ? tG.y : tG.x);
    int vO = s2 ? (s1 ? tO.w : tO.z) : (s1 ? tO.y : tO.x);
    float ri = (float)vI * fI + gv.x;
    float rf = (float)vF * fF + gv.y;
    float rg = (float)vG * fG + gv.z;
    float ro = (float)vO * fO + gv.w;
    float is = sigf(ri), fs = sigf(rf);
    float gt = tanhf_fast(rg), os = sigf(ro);
    c = fs * c + is * gt;                   // lanes lr>=8 mirror lr-8 (harmless)
    float hv = os * tanhf_fast(c);
    if (lr < 8) {
      int time = dir ? (8191 - t) : t;
      hout[(size_t)time * 256 + u] = hv;    // queues; drained at chunk end
    }
    // pack 4 units' int8 into one dword via DPP quad-add (disjoint bytes)
    int q = ((int)rintf(hv * 127.f)) & 255;
    int x = q << (r_l * 8);
#if __has_builtin(__builtin_amdgcn_mov_dpp)
    x += __builtin_amdgcn_mov_dpp(x, 0xB1, 0xF, 0xF, true);  // quad_perm xor1
    x += __builtin_amdgcn_mov_dpp(x, 0x4E, 0xF, 0xF, true);  // quad_perm xor2
#else
    x += __shfl_xor(x, 1);
    x += __shfl_xor(x, 2);
#endif
    if (r_l == 0 && lr < 8) bufW[u >> 2] = x;   // dwords 8w+4h+lg, distinct
  };

  // prologue: stage chunk 0, drain, sync
  stage(0);
  asm volatile("s_waitcnt vmcnt(0)" ::: "memory");
  __syncthreads();

  int cur = 0;
  for (int cn = 0; cn < 2048; ++cn) {
    if (cn + 1 < 2048) stage(cn + 1);       // writes the OTHER half; WAR-safe
    const float* Hc = GL[cn & 1];
#pragma unroll
    for (int s = 0; s < 4; ++s) {
      int row = dir ? (3 - s) : s;
      step((cn << 2) + s, Hc + (row << 10), h8c[cur], h8c[cur ^ 1]);
      cur ^= 1;
      if (s == 3) {
        // chunk boundary: drain staging once per 4 steps
        asm volatile("s_waitcnt vmcnt(0) lgkmcnt(0)\n\ts_barrier" ::: "memory");
      } else {
        barrier_lds();                       // the ONE barrier per step
      }
    }
  }
}

// ---------------------------------------------------------------------------
// Kernel 4: feats = [hf | hb] @ W_out.T + b_out.
// ---------------------------------------------------------------------------
__global__ void k_feats(const float* __restrict__ hf, const float* __restrict__ hb,
                        const float* __restrict__ W_out, const float* __restrict__ b_out,
                        float* __restrict__ feats){
  int t0 = blockIdx.x * 16;
  for (int oi = threadIdx.x; oi < 16 * NT; oi += 256) {
    int tt = oi / NT;
    int tag = oi - tt * NT;
    int t = t0 + tt;
    const float4* w4 = (const float4*)(W_out + (size_t)tag * 512);
    const float4* a4 = (const float4*)(hf + (size_t)t * 256);
    const float4* c4 = (const float4*)(hb + (size_t)t * 256);
    float acc = b_out[tag];
    for (int k = 0; k < 64; k++) {
      float4 w = w4[k]; float4 h = a4[k];
      acc += w.x * h.x + w.y * h.y + w.z * h.z + w.w * h.w;
    }
    for (int k = 0; k < 64; k++) {
      float4 w = w4[64 + k]; float4 h = c4[k];
      acc += w.x * h.x + w.y * h.y + w.z * h.z + w.w * h.w;
    }
    feats[(size_t)t * NT + tag] = acc;
  }
}

// ---------------------------------------------------------------------------
// CRF as a chunked associative scan in the (lse,+) semiring, log2-domain.
// alpha: M_t[j][i] = λ(tr[j][i] + feat_t[j]);  alpha_t = M_t ⊗ alpha_{t-1}
// beta : N_t[j][i] = λ(tr[i][j] + feat_{t+1}[i]); beta_t = N_t ⊗ beta_{t+1},
//        N_{L-1} = identity, virtual beta_L[j] = lse_i λ tr[i][j].
// Phase 1: per-chunk matrix products (128 chunks x 2 dirs, parallel).
// Phase 2: sequential matvec prefix over 128 chunk products (2 blocks).
// Phase 3: per-chunk vector re-scan emitting wsA/wsB (parallel).
// ---------------------------------------------------------------------------
__global__ __launch_bounds__(320) void k_crf_p1(const float* __restrict__ feats,
                                                const float* __restrict__ trans,
                                                float* __restrict__ Pg,
                                                float* __restrict__ rmaxG){
  int dir = blockIdx.x >> 7;
  int c   = blockIdx.x & (CCH - 1);
  int tid = threadIdx.x;
  int t0  = c * SCH;

  __shared__ __align__(16) float TRM[NT * NP];
  __shared__ float Fe[(SCH + 1) * NT];
  __shared__ __align__(16) float Pbuf[2][NT * NP];
  __shared__ float CM[NP];
  __shared__ float RMs[NT];

  for (int idx = tid; idx < NT * NT; idx += 320) {
    int j = idx / NT, k = idx - j * NT;
    float v = (dir == 0) ? trans[j * NT + k] : trans[k * NT + j];
    TRM[j * NP + k] = v * F_L2E;
  }
  for (int idx = tid; idx < (SCH + 1) * NT; idx += 320) {
    int s = idx / NT, j = idx - s * NT;
    int t = t0 + s; if (t > LSEQ - 1) t = LSEQ - 1;
    Fe[idx] = feats[(size_t)t * NT + j] * F_L2E;
  }
  for (int idx = tid; idx < NT * NP; idx += 320) {
    int k = idx / NP, i = idx - k * NP;
    Pbuf[0][idx] = (i < NT && i == k) ? 0.f : -1e30f;
  }
  if (tid < NP) CM[tid] = (tid < NT) ? 0.f : -1e30f;
  __syncthreads();
  if (tid < NT) {
    float m = -3e38f;
    for (int k = 0; k < NT; k++) m = fmaxf(m, TRM[tid * NP + k]);
    RMs[tid] = m;
  }
  __syncthreads();
  for (int idx = tid; idx < NT * NT; idx += 320) {
    int j = idx / NT, k = idx - j * NT;
    TRM[j * NP + k] -= RMs[j];
  }
  __syncthreads();

  int cur = 0;
  int j = tid / 9, g = tid - (tid / 9) * 9;
  bool act = (tid < 306);
  int i0 = 4 * g;

  for (int s = 0; s < SCH; s++) {
    int t = (dir == 0) ? (t0 + s) : (t0 + SCH - 1 - s);
    if (dir == 1 && t == LSEQ - 1) continue;   // identity factor at t=L-1
    const float* Pc = Pbuf[cur];
    float* Pn = Pbuf[cur ^ 1];
    if (act) {
      float cm0 = CM[i0], cm1 = CM[i0 + 1], cm2 = CM[i0 + 2], cm3 = CM[i0 + 3];
      float s0 = 0, s1 = 0, s2 = 0, s3 = 0;
      const float* trp = TRM + j * NP;
      const float* fep = Fe + (t + 1 - t0) * NT;   // only read when dir==1
#pragma unroll
      for (int k = 0; k < NT; k++) {
        float trv = trp[k];
        if (dir == 1) trv += fep[k];
        float4 p = *(const float4*)&Pc[k * NP + i0];
        s0 += ex2(trv + p.x - cm0);
        s1 += ex2(trv + p.y - cm1);
        s2 += ex2(trv + p.z - cm2);
        s3 += ex2(trv + p.w - cm3);
      }
      float base = RMs[j] + ((dir == 0) ? Fe[(t - t0) * NT + j] : 0.f);
      float4 o;
      o.x = base + cm0 + lg2(s0);
      o.y = base + cm1 + lg2(s1);
      o.z = (i0 + 2 < NT) ? (base + cm2 + lg2(s2)) : -1e30f;
      o.w = (i0 + 3 < NT) ? (base + cm3 + lg2(s3)) : -1e30f;
      *(float4*)&Pn[j * NP + i0] = o;
    }
    __syncthreads();
    if (tid < NP) {
      float m = -3e38f;
      const float* col = Pn + tid;
      for (int k = 0; k < NT; k++) m = fmaxf(m, col[k * NP]);
      CM[tid] = m;
    }
    cur ^= 1;
    __syncthreads();
  }

  const float* Pf = Pbuf[cur];
  size_t base = (size_t)((dir << 7) + c) * (NT * NP);
  for (int idx = tid; idx < NT * NP; idx += 320)
    Pg[base + idx] = Pf[idx];
  if (tid < NT) {
    float m = -3e38f;
    for (int i = 0; i < NT; i++) m = fmaxf(m, Pf[tid * NP + i]);
    rmaxG[((dir << 7) + c) * NT + tid] = m;
  }
}

__global__ void k_crf_p2(const float* __restrict__ trans,
                         const float* __restrict__ Pg,
                         const float* __restrict__ rmaxG,
                         float* __restrict__ vIn){
  int dir = blockIdx.x;
  int lane = threadIdx.x;           // 64, single wave
  bool a = (lane < NT);
  int j = a ? lane : 0;
  __shared__ float V[NP];

  float v;
  if (dir == 0) {
    v = (lane == 32) ? 0.f : -10000.f * F_L2E;
  } else {
    float m = -3e38f;
    for (int i = 0; i < NT; i++) m = fmaxf(m, trans[i * NT + j]);
    float s = 0.f;
    for (int i = 0; i < NT; i++) s += ex2((trans[i * NT + j] - m) * F_L2E);
    v = m * F_L2E + lg2(s);
  }
  if (lane < NP) V[lane] = -1e30f;
  barrier_lds();
  if (a) V[j] = v;
  barrier_lds();
  float vm = a ? v : -3e38f;
  for (int off = 32; off; off >>= 1) vm = fmaxf(vm, __shfl_xor(vm, off));

  if (a) {
    int c0 = (dir == 0) ? 0 : (CCH - 1);
    vIn[((size_t)(dir << 7) + c0) * NP + j] = v;
  }

  for (int it = 0; it < CCH - 1; it++) {
    int c = (dir == 0) ? it : (CCH - 1 - it);
    const float* row = Pg + ((size_t)(dir << 7) + c) * (NT * NP) + j * NP;
    float rm = rmaxG[((dir << 7) + c) * NT + j];
    float m = rm + vm;
    float s = 0.f;
#pragma unroll
    for (int k = 0; k < NP; k += 4) {
      float4 p = *(const float4*)&row[k];
      s += ex2(p.x + V[k]     - m);
      s += ex2(p.y + V[k + 1] - m);
      s += ex2(p.z + V[k + 2] - m);
      s += ex2(p.w + V[k + 3] - m);
    }
    float nv = m + lg2(s);
    if (a) V[j] = nv;
    barrier_lds();
    float x = a ? nv : -3e38f;
    for (int off = 32; off; off >>= 1) x = fmaxf(x, __shfl_xor(x, off));
    vm = x;
    int cn = (dir == 0) ? (c + 1) : (c - 1);
    if (a) vIn[((size_t)(dir << 7) + cn) * NP + j] = nv;
  }
}

__global__ void k_crf_p3(const float* __restrict__ feats,
                         const float* __restrict__ trans,
                         const float* __restrict__ vIn,
                         float* __restrict__ wsA,
                         float* __restrict__ wsB){
  int dir = blockIdx.x >> 7;
  int c   = blockIdx.x & (CCH - 1);
  int lane = threadIdx.x;           // 64, single wave
  int t0 = c * SCH;
  bool a = (lane < NT);
  int j = a ? lane : 0;
  __shared__ float A[NP];
  __shared__ float U[NP];

  float trr[NT];
  float rm = -3e38f;
#pragma unroll
  for (int k = 0; k < NT; k++) {
    float vv = (dir == 0) ? trans[j * NT + k] : trans[k * NT + j];
    trr[k] = vv * F_L2E;
    rm = fmaxf(rm, trr[k]);
  }
  if (lane < NP) { A[lane] = -1e30f; U[lane] = -1e30f; }
  float v0 = vIn[((size_t)(dir << 7) + c) * NP + j];
  barrier_lds();
  if (a) A[j] = v0;
  barrier_lds();
  float am = a ? v0 : -3e38f;
  for (int off = 32; off; off >>= 1) am = fmaxf(am, __shfl_xor(am, off));

  if (dir == 0) {
    float fe = feats[(size_t)t0 * NT + j] * F_L2E;
    for (int s = 0; s < SCH; s++) {
      int t = t0 + s;
      int tn = (t + 1 < LSEQ) ? t + 1 : LSEQ - 1;
      float fe_n = feats[(size_t)tn * NT + j] * F_L2E;
      float m = rm + am;
      float ss = 0.f;
#pragma unroll
      for (int k = 0; k < NT; k++) ss += ex2(trr[k] + A[k] - m);
      float out = m + lg2(ss) + fe;
      if (a) wsA[(size_t)t * NT + j] = out * F_LN2;
      if (a) A[j] = out;
      barrier_lds();
      float x = a ? out : -3e38f;
      for (int off = 32; off; off >>= 1) x = fmaxf(x, __shfl_xor(x, off));
      am = x;
      fe = fe_n;
    }
  } else {
    float b = v0;                    // beta_{t+1}, per-lane register
    int tfirst = t0 + SCH; if (tfirst > LSEQ - 1) tfirst = LSEQ - 1;
    float fe = feats[(size_t)tfirst * NT + j] * F_L2E;   // feat_{t+1} for first step
    for (int s = 0; s < SCH; s++) {
      int t = t0 + SCH - 1 - s;
      float fe_n = feats[(size_t)t * NT + j] * F_L2E;    // next step's feat_{t+1}
      float out;
      if (t == LSEQ - 1) {
        out = b;                     // identity factor
      } else {
        if (a) U[j] = b + fe;
        barrier_lds();
        float um = a ? U[j] : -3e38f;
        for (int off = 32; off; off >>= 1) um = fmaxf(um, __shfl_xor(um, off));
        float m = rm + um;
        float ss = 0.f;
#pragma unroll
        for (int k = 0; k < NT; k++) ss += ex2(trr[k] + U[k] - m);
        out = m + lg2(ss);
        barrier_lds();
      }
      if (a) wsB[(size_t)t * NT + j] = out * F_LN2;
      b = out;
      fe = fe_n;
    }
  }
}

// ---------------------------------------------------------------------------
// Kernel: score = alpha + beta; tags = argmax.
// ---------------------------------------------------------------------------
__global__ void k_finish(const float* __restrict__ wsA, const float* __restrict__ wsB,
                         float* __restrict__ out){
  int t = blockIdx.x * 256 + threadIdx.x;
  float m = -3e38f; int bi = 0;
  for (int i = 0; i < NT; i++) {
    float sc = wsA[(size_t)t * NT + i] + wsB[(size_t)t * NT + i];
    out[(size_t)t * NT + i] = sc;
    if (sc > m) { m = sc; bi = i; }
  }
  out[(size_t)LSEQ * NT + t] = (float)bi;
}

// ---------------------------------------------------------------------------
extern "C" void kernel_launch(void* const* d_in, const int* in_sizes, int n_in,
                              void* d_out, int out_size, void* d_ws, size_t ws_size,
                              hipStream_t stream) {
  const int*   words  = (const int*)  d_in[0];
  const float* embed  = (const float*)d_in[1];
  const float* Wih_f  = (const float*)d_in[2];
  const float* Whh_f  = (const float*)d_in[3];
  const float* b_f    = (const float*)d_in[4];
  const float* Wih_b  = (const float*)d_in[5];
  const float* Whh_b  = (const float*)d_in[6];
  const float* b_b    = (const float*)d_in[7];
  const float* W_out  = (const float*)d_in[8];
  const float* b_out  = (const float*)d_in[9];
  const float* trans  = (const float*)d_in[10];
  float* out = (float*)d_out;

  float* wsf = (float*)d_ws;
  size_t off = 0;
  float* G_f   = wsf + off; off += (size_t)LSEQ * 1024;
  float* G_b   = wsf + off; off += (size_t)LSEQ * 1024;
  float* hf    = wsf + off; off += (size_t)LSEQ * 256;
  float* hb    = wsf + off; off += (size_t)LSEQ * 256;
  float* feats = wsf + off; off += (size_t)LSEQ * NT + 16;
  float* wsA   = wsf + off; off += (size_t)LSEQ * NT + 16;
  float* wsB   = wsf + off; off += (size_t)LSEQ * NT + 16;
  float* fac   = wsf + off; off += 2048;
  int*   Wq    = (int*)(wsf + off); off += 2 * 1024 * 64;
  // CRF scan scratch overlaps G_f (dead after k_lstm)
  float* Pg    = G_f;                                   // 256 * 34*36
  float* rmaxG = G_f + 256 * (NT * NP);                 // 256 * 34
  float* vIn   = rmaxG + 256 * NT + 32;                 // 256 * 36

  k_quant<<<2048, 64, 0, stream>>>(Whh_f, Whh_b, Wq, fac);
  k_gproj<<<dim3(512, 2), 256, 0, stream>>>(words, embed, Wih_f, b_f, Wih_b, b_b, G_f, G_b);
  k_lstm<<<2, 512, 0, stream>>>(Wq, fac, G_f, G_b, hf, hb);
  k_feats<<<512, 256, 0, stream>>>(hf, hb, W_out, b_out, feats);
  k_crf_p1<<<256, 320, 0, stream>>>(feats, trans, Pg, rmaxG);
  k_crf_p2<<<2, 64, 0, stream>>>(trans, Pg, rmaxG, vIn);
  k_crf_p3<<<256, 64, 0, stream>>>(feats, trans, vIn, wsA, wsB);
  k_finish<<<32, 256, 0, stream>>>(wsA, wsB, out);
}

// Round 9
// 8127.587 us; speedup vs baseline: 1.4261x; 1.0322x over previous
//
#include <hip/hip_runtime.h>
#include <cstdint>
#include <cstddef>

#define LSEQ 8192
#define NT   34
#define NP   36
#define SCH  64
#define CCH  128
#define F_L2E 1.4426950408889634f
#define F_LN2 0.6931471805599453f

typedef int v4i __attribute__((ext_vector_type(4)));

#if __has_builtin(__builtin_amdgcn_global_load_lds)
#define HAS_GLL 1
#else
#define HAS_GLL 0
#endif

// int8 MFMA. Builtin REQUIRED for correctness: the compiler inserts the
// mandatory MFMA->VALU/DS hazard wait-states (s_nop). R6's raw inline asm
// bypassed the hazard recognizer -> stale accumulator reads -> absmax 19.
#if __has_builtin(__builtin_amdgcn_mfma_i32_16x16x64_i8)
#define MFMA_I8(a,b,c) __builtin_amdgcn_mfma_i32_16x16x64_i8((a),(b),(c),0,0,0)
#else
__device__ __forceinline__ v4i mfma_i8_asm(v4i a, v4i b, v4i c){
  asm volatile("v_mfma_i32_16x16x64_i8 %0, %1, %2, %0\n\ts_nop 7\n\ts_nop 7"
               : "+v"(c) : "v"(a), "v"(b));
  return c;
}
#define MFMA_I8(a,b,c) mfma_i8_asm((a),(b),(c))
#endif

__device__ __forceinline__ float ex2(float x){
#if __has_builtin(__builtin_amdgcn_exp2f)
  return __builtin_amdgcn_exp2f(x);
#else
  return exp2f(x);
#endif
}
__device__ __forceinline__ float lg2(float x){
#if __has_builtin(__builtin_amdgcn_logf)
  return __builtin_amdgcn_logf(x);   // v_log_f32 = log2
#else
  return __log2f(x);
#endif
}

__device__ __forceinline__ float sigf(float x){
  return __fdividef(1.f, 1.f + ex2(-F_L2E * x));
}
__device__ __forceinline__ float tanhf_fast(float x){
  return 1.f - __fdividef(2.f, ex2(2.f * F_L2E * x) + 1.f);
}

// barrier without the vmcnt(0) drain: LDS-only fence + s_barrier.
__device__ __forceinline__ void barrier_lds(){
  asm volatile("s_waitcnt lgkmcnt(0)\n\ts_barrier" ::: "memory");
}

// ---------------------------------------------------------------------------
// Kernel 1: quantize Whh (both dirs) to int8 with per-row scale.
// ---------------------------------------------------------------------------
__global__ void k_quant(const float* __restrict__ Whh_f,
                        const float* __restrict__ Whh_b,
                        int* __restrict__ Wq, float* __restrict__ fac){
  int bid = blockIdx.x;
  int dir = bid >> 10;
  int r   = bid & 1023;
  int i   = threadIdx.x;           // 0..63
  const float* W = (dir ? Whh_b : Whh_f) + r * 256 + i * 4;
  float w0 = W[0], w1 = W[1], w2 = W[2], w3 = W[3];
  float m = fmaxf(fmaxf(fabsf(w0), fabsf(w1)), fmaxf(fabsf(w2), fabsf(w3)));
  for (int s = 32; s; s >>= 1) m = fmaxf(m, __shfl_xor(m, s));
  float scale = (m > 0.f) ? m / 127.f : 1.f;
  float inv = __fdividef(1.f, scale);
  int q0 = (int)rintf(w0 * inv), q1 = (int)rintf(w1 * inv);
  int q2 = (int)rintf(w2 * inv), q3 = (int)rintf(w3 * inv);
  q0 = max(-127, min(127, q0)); q1 = max(-127, min(127, q1));
  q2 = max(-127, min(127, q2)); q3 = max(-127, min(127, q3));
  int p = (q0 & 255) | ((q1 & 255) << 8) | ((q2 & 255) << 16) | ((q3 & 255) << 24);
  Wq[(dir << 16) + (r << 6) + i] = p;
  if (i == 0) fac[(dir << 10) + r] = scale * (1.f / 127.f);
}

// ---------------------------------------------------------------------------
// Kernel 2: G[t][u*4+gate] = b[r] + sum_e embed[words[t]][e] * Wih[r][e]
// (gate-interleaved output layout so k_lstm reads one float4 per unit;
//  verified correct in R5/R7, absmax 0)
// ---------------------------------------------------------------------------
__global__ void k_gproj(const int* __restrict__ words,
                        const float* __restrict__ embed,
                        const float* __restrict__ Wih_f, const float* __restrict__ b_f,
                        const float* __restrict__ Wih_b, const float* __restrict__ b_b,
                        float* __restrict__ G_f, float* __restrict__ G_b){
  int dir = blockIdx.y;
  const float* Wih = dir ? Wih_b : Wih_f;
  const float* bb  = dir ? b_b  : b_f;
  float* G = dir ? G_b : G_f;
  int t0 = blockIdx.x * 16;
  __shared__ __align__(16) float X[16 * 256];
  for (int idx = threadIdx.x; idx < 16 * 256; idx += 256) {
    int tt = idx >> 8, e = idx & 255;
    X[idx] = embed[(size_t)words[t0 + tt] * 256 + e];
  }
  __syncthreads();
  const float4* X4 = (const float4*)X;
  for (int rb = 0; rb < 4; rb++) {
    int r = rb * 256 + threadIdx.x;      // gate rb, unit threadIdx.x
    float bv = bb[r];
    float acc[16];
#pragma unroll
    for (int tt = 0; tt < 16; tt++) acc[tt] = bv;
    const float4* W4 = (const float4*)(Wih + (size_t)r * 256);
    for (int eb = 0; eb < 64; eb++) {
      float4 w = W4[eb];
#pragma unroll
      for (int tt = 0; tt < 16; tt++) {
        float4 x = X4[tt * 64 + eb];
        acc[tt] += w.x * x.x + w.y * x.y + w.z * x.z + w.w * x.w;
      }
    }
    for (int tt = 0; tt < 16; tt++)
      G[(size_t)(t0 + tt) * 1024 + (threadIdx.x << 2) + rb] = acc[tt];
  }
}

// ---------------------------------------------------------------------------
// Kernel 3: LSTM recurrences. block 0 = forward, block 1 = backward.
// R7 (absmax 0) + K-OUTER MFMA ISSUE ORDER. R7's counters: MfmaUtil 47% x
// 2179 cyc/step = 1024 = exactly the 64-MFMA/SIMD pipe floor; the other
// ~1150 cyc matched a dependent-chain-stall model (tile-inner source order:
// 8 chains of 4 back-to-back dependent MFMAs, ~18 cyc stall per dependent
// issue). K-outer order makes consecutive MFMAs independent (a tile's next-K
// MFMA comes 8 instructions later >> the dependent-use latency) so each wave
// issues at pipe rate. Numerically identical (same MFMAs, same int32
// accumulation per tile -- pure reorder).
// NOTE R8 never ran: broker "container failed twice" with zero kernel-side
// mechanism (identical LDS/launch/live-ranges to R7, which passed). Infra
// flake; resubmitting the same experiment.
// Broadcast-B identity: D's 16 cols are equal, so every lane of 16-group lg
// holds gate sums of units 32w+16h+4lg+reg for all 4 gates in registers;
// lane lr statically selects (h=lr>>2&1, r=lr&3) and runs the gates for ONE
// unit; 32 lanes x 8 waves = 256 units. ONE barrier/step. G staged in 4-step
// chunks (2x16KB) via global_load_lds, one vmcnt(0) drain per chunk.
// ---------------------------------------------------------------------------
__global__ __launch_bounds__(512, 2) void k_lstm(const int* __restrict__ Wq,
                                                 const float* __restrict__ fac,
                                                 const float* __restrict__ G_f,
                                                 const float* __restrict__ G_b,
                                                 float* __restrict__ hf,
                                                 float* __restrict__ hb){
  int dir = blockIdx.x;
  const int* Wqd = Wq + (dir << 16);
  const float* facp = fac + (dir << 10);
  const float* G = dir ? G_b : G_f;
  float* hout = dir ? hb : hf;
  int tid = threadIdx.x;
  int ln  = tid & 63;            // lane
  int wv  = tid >> 6;            // wave 0..7
  int lg  = ln >> 4;             // 16-lane group = K-chunk = D row-group
  int lr  = ln & 15;             // A row within tile
  int h_l = (lr >> 2) & 1;       // this lane's half-tile (lanes 8..15 mirror 0..7)
  int r_l = lr & 3;              // this lane's reg index within D row-group
  int u   = (wv << 5) + (h_l << 4) + (lg << 2) + r_l;   // unit this lane owns

  __shared__ __align__(16) float GL[2][4 * 1024];   // 2 x 16KB G staging
  __shared__ __align__(16) int h8c[2][64];          // 2 x 256 int8 h

  // A operands: 8 tiles (gate g, half h) x 4 K-slices; 128 regs.
  v4i wgt[4][2][4];
#pragma unroll
  for (int g = 0; g < 4; g++)
#pragma unroll
    for (int h = 0; h < 2; h++) {
      int R = g * 256 + (wv << 5) + (h << 4) + lr;
#pragma unroll
      for (int ks = 0; ks < 4; ks++)
        wgt[g][h][ks] = *(const v4i*)(Wqd + R * 64 + ks * 16 + lg * 4);
    }

  float fI = facp[u], fF = facp[u + 256], fG = facp[u + 512], fO = facp[u + 768];
  if (tid < 64) h8c[0][tid] = 0;
  float c = 0.f;
  v4i zero = {0, 0, 0, 0};

  // stage chunk cn (4 timesteps = 16KB contiguous) into GL[cn&1].
  auto stage = [&](int cn) {
    int half = cn & 1;
    int gt0 = dir ? (8191 - (cn * 4 + 3)) : (cn * 4);
    const char* src = (const char*)(G + (size_t)gt0 * 1024) + (wv << 11) + (ln << 4);
    char* dst = (char*)&GL[half][0] + (wv << 11);
#pragma unroll
    for (int i = 0; i < 2; i++) {
#if HAS_GLL
      __builtin_amdgcn_global_load_lds(
          (const __attribute__((address_space(1))) unsigned int*)(src + (i << 10)),
          (__attribute__((address_space(3))) unsigned int*)(dst + (i << 10)),
          16, 0, 0);
#else
      *(float4*)(dst + (i << 10) + (ln << 4)) = *(const float4*)(src + (i << 10));
#endif
    }
  };

  auto step = [&](int t, const float* Grow, const int* bufR, int* bufW) {
    // B operand: h bytes [ks*64 + lg*16 .. +15]; 16-lane shared addr = broadcast
    const v4i* hb4 = (const v4i*)bufR;
    v4i b0 = hb4[lg], b1 = hb4[4 + lg], b2 = hb4[8 + lg], b3 = hb4[12 + lg];
    float4 gv = ((const float4*)Grow)[u];   // issued early, overlaps MFMA
    v4i res[4][2];
    // K-OUTER: 8 independent MFMAs per K-slice; pipe-rate issue, no
    // dependent-chain stalls. ks=0 seeds from zero.
#pragma unroll
    for (int g = 0; g < 4; g++)
#pragma unroll
      for (int h = 0; h < 2; h++)
        res[g][h] = MFMA_I8(wgt[g][h][0], b0, zero);
#pragma unroll
    for (int g = 0; g < 4; g++)
#pragma unroll
      for (int h = 0; h < 2; h++)
        res[g][h] = MFMA_I8(wgt[g][h][1], b1, res[g][h]);
#pragma unroll
    for (int g = 0; g < 4; g++)
#pragma unroll
      for (int h = 0; h < 2; h++)
        res[g][h] = MFMA_I8(wgt[g][h][2], b2, res[g][h]);
#pragma unroll
    for (int g = 0; g < 4; g++)
#pragma unroll
      for (int h = 0; h < 2; h++)
        res[g][h] = MFMA_I8(wgt[g][h][3], b3, res[g][h]);
    // static cndmask selection of this lane's unit from its 8 tiles
    bool sh = h_l != 0;
    bool s1 = (r_l & 1) != 0;
    bool s2 = (r_l & 2) != 0;
    v4i tI = sh ? res[0][1] : res[0][0];
    v4i tF = sh ? res[1][1] : res[1][0];
    v4i tG = sh ? res[2][1] : res[2][0];
    v4i tO = sh ? res[3][1] : res[3][0];
    int vI = s2 ? (s1 ? tI.w : tI.z) : (s1 ? tI.y : tI.x);
    int vF = s2 ? (s1 ? tF.w : tF.z) : (s1 ? tF.y : tF.x);
    int vG = s2 ? (s1 ? tG.w : tG.z) : (s1 ? tG.y : tG.x);
    int vO = s2 ? (s1 ? tO.w : tO.z) : (s1 ? tO.y : tO.x);
    float ri = (float)vI * fI + gv.x;
    float rf = (float)vF * fF + gv.y;
    float rg = (float)vG * fG + gv.z;
    float ro = (float)vO * fO + gv.w;
    float is = sigf(ri), fs = sigf(rf);
    float gt = tanhf_fast(rg), os = sigf(ro);
    c = fs * c + is * gt;                   // lanes lr>=8 mirror lr-8 (harmless)
    float hv = os * tanhf_fast(c);
    // LDS path FIRST (barrier waits lgkmcnt; the global store is un-waited)
    int q = ((int)rintf(hv * 127.f)) & 255;
    int x = q << (r_l * 8);
#if __has_builtin(__builtin_amdgcn_mov_dpp)
    x += __builtin_amdgcn_mov_dpp(x, 0xB1, 0xF, 0xF, true);  // quad_perm xor1
    x += __builtin_amdgcn_mov_dpp(x, 0x4E, 0xF, 0xF, true);  // quad_perm xor2
#else
    x += __shfl_xor(x, 1);
    x += __shfl_xor(x, 2);
#endif
    if (r_l == 0 && lr < 8) bufW[u >> 2] = x;   // dwords 8w+4h+lg, distinct
    if (lr < 8) {
      int time = dir ? (8191 - t) : t;
      hout[(size_t)time * 256 + u] = hv;    // queues; drained at chunk end
    }
  };

  // prologue: stage chunk 0, drain, sync
  stage(0);
  asm volatile("s_waitcnt vmcnt(0)" ::: "memory");
  __syncthreads();

  int cur = 0;
  for (int cn = 0; cn < 2048; ++cn) {
    if (cn + 1 < 2048) stage(cn + 1);       // writes the OTHER half; WAR-safe
    const float* Hc = GL[cn & 1];
#pragma unroll
    for (int s = 0; s < 4; ++s) {
      int row = dir ? (3 - s) : s;
      step((cn << 2) + s, Hc + (row << 10), h8c[cur], h8c[cur ^ 1]);
      cur ^= 1;
      if (s == 3) {
        // chunk boundary: drain staging once per 4 steps
        asm volatile("s_waitcnt vmcnt(0) lgkmcnt(0)\n\ts_barrier" ::: "memory");
      } else {
        barrier_lds();                       // the ONE barrier per step
      }
    }
  }
}

// ---------------------------------------------------------------------------
// Kernel 4: feats = [hf | hb] @ W_out.T + b_out.
// ---------------------------------------------------------------------------
__global__ void k_feats(const float* __restrict__ hf, const float* __restrict__ hb,
                        const float* __restrict__ W_out, const float* __restrict__ b_out,
                        float* __restrict__ feats){
  int t0 = blockIdx.x * 16;
  for (int oi = threadIdx.x; oi < 16 * NT; oi += 256) {
    int tt = oi / NT;
    int tag = oi - tt * NT;
    int t = t0 + tt;
    const float4* w4 = (const float4*)(W_out + (size_t)tag * 512);
    const float4* a4 = (const float4*)(hf + (size_t)t * 256);
    const float4* c4 = (const float4*)(hb + (size_t)t * 256);
    float acc = b_out[tag];
    for (int k = 0; k < 64; k++) {
      float4 w = w4[k]; float4 h = a4[k];
      acc += w.x * h.x + w.y * h.y + w.z * h.z + w.w * h.w;
    }
    for (int k = 0; k < 64; k++) {
      float4 w = w4[64 + k]; float4 h = c4[k];
      acc += w.x * h.x + w.y * h.y + w.z * h.z + w.w * h.w;
    }
    feats[(size_t)t * NT + tag] = acc;
  }
}

// ---------------------------------------------------------------------------
// CRF as a chunked associative scan in the (lse,+) semiring, log2-domain.
// alpha: M_t[j][i] = λ(tr[j][i] + feat_t[j]);  alpha_t = M_t ⊗ alpha_{t-1}
// beta : N_t[j][i] = λ(tr[i][j] + feat_{t+1}[i]); beta_t = N_t ⊗ beta_{t+1},
//        N_{L-1} = identity, virtual beta_L[j] = lse_i λ tr[i][j].
// Phase 1: per-chunk matrix products (128 chunks x 2 dirs, parallel).
// Phase 2: sequential matvec prefix over 128 chunk products (2 blocks).
// Phase 3: per-chunk vector re-scan emitting wsA/wsB (parallel).
// ---------------------------------------------------------------------------
__global__ __launch_bounds__(320) void k_crf_p1(const float* __restrict__ feats,
                                                const float* __restrict__ trans,
                                                float* __restrict__ Pg,
                                                float* __restrict__ rmaxG){
  int dir = blockIdx.x >> 7;
  int c   = blockIdx.x & (CCH - 1);
  int tid = threadIdx.x;
  int t0  = c * SCH;

  __shared__ __align__(16) float TRM[NT * NP];
  __shared__ float Fe[(SCH + 1) * NT];
  __shared__ __align__(16) float Pbuf[2][NT * NP];
  __shared__ float CM[NP];
  __shared__ float RMs[NT];

  for (int idx = tid; idx < NT * NT; idx += 320) {
    int j = idx / NT, k = idx - j * NT;
    float v = (dir == 0) ? trans[j * NT + k] : trans[k * NT + j];
    TRM[j * NP + k] = v * F_L2E;
  }
  for (int idx = tid; idx < (SCH + 1) * NT; idx += 320) {
    int s = idx / NT, j = idx - s * NT;
    int t = t0 + s; if (t > LSEQ - 1) t = LSEQ - 1;
    Fe[idx] = feats[(size_t)t * NT + j] * F_L2E;
  }
  for (int idx = tid; idx < NT * NP; idx += 320) {
    int k = idx / NP, i = idx - k * NP;
    Pbuf[0][idx] = (i < NT && i == k) ? 0.f : -1e30f;
  }
  if (tid < NP) CM[tid] = (tid < NT) ? 0.f : -1e30f;
  __syncthreads();
  if (tid < NT) {
    float m = -3e38f;
    for (int k = 0; k < NT; k++) m = fmaxf(m, TRM[tid * NP + k]);
    RMs[tid] = m;
  }
  __syncthreads();
  for (int idx = tid; idx < NT * NT; idx += 320) {
    int j = idx / NT, k = idx - j * NT;
    TRM[j * NP + k] -= RMs[j];
  }
  __syncthreads();

  int cur = 0;
  int j = tid / 9, g = tid - (tid / 9) * 9;
  bool act = (tid < 306);
  int i0 = 4 * g;

  for (int s = 0; s < SCH; s++) {
    int t = (dir == 0) ? (t0 + s) : (t0 + SCH - 1 - s);
    if (dir == 1 && t == LSEQ - 1) continue;   // identity factor at t=L-1
    const float* Pc = Pbuf[cur];
    float* Pn = Pbuf[cur ^ 1];
    if (act) {
      float cm0 = CM[i0], cm1 = CM[i0 + 1], cm2 = CM[i0 + 2], cm3 = CM[i0 + 3];
      float s0 = 0, s1 = 0, s2 = 0, s3 = 0;
      const float* trp = TRM + j * NP;
      const float* fep = Fe + (t + 1 - t0) * NT;   // only read when dir==1
#pragma unroll
      for (int k = 0; k < NT; k++) {
        float trv = trp[k];
        if (dir == 1) trv += fep[k];
        float4 p = *(const float4*)&Pc[k * NP + i0];
        s0 += ex2(trv + p.x - cm0);
        s1 += ex2(trv + p.y - cm1);
        s2 += ex2(trv + p.z - cm2);
        s3 += ex2(trv + p.w - cm3);
      }
      float base = RMs[j] + ((dir == 0) ? Fe[(t - t0) * NT + j] : 0.f);
      float4 o;
      o.x = base + cm0 + lg2(s0);
      o.y = base + cm1 + lg2(s1);
      o.z = (i0 + 2 < NT) ? (base + cm2 + lg2(s2)) : -1e30f;
      o.w = (i0 + 3 < NT) ? (base + cm3 + lg2(s3)) : -1e30f;
      *(float4*)&Pn[j * NP + i0] = o;
    }
    __syncthreads();
    if (tid < NP) {
      float m = -3e38f;
      const float* col = Pn + tid;
      for (int k = 0; k < NT; k++) m = fmaxf(m, col[k * NP]);
      CM[tid] = m;
    }
    cur ^= 1;
    __syncthreads();
  }

  const float* Pf = Pbuf[cur];
  size_t base = (size_t)((dir << 7) + c) * (NT * NP);
  for (int idx = tid; idx < NT * NP; idx += 320)
    Pg[base + idx] = Pf[idx];
  if (tid < NT) {
    float m = -3e38f;
    for (int i = 0; i < NT; i++) m = fmaxf(m, Pf[tid * NP + i]);
    rmaxG[((dir << 7) + c) * NT + tid] = m;
  }
}

__global__ void k_crf_p2(const float* __restrict__ trans,
                         const float* __restrict__ Pg,
                         const float* __restrict__ rmaxG,
                         float* __restrict__ vIn){
  int dir = blockIdx.x;
  int lane = threadIdx.x;           // 64, single wave
  bool a = (lane < NT);
  int j = a ? lane : 0;
  __shared__ float V[NP];

  float v;
  if (dir == 0) {
    v = (lane == 32) ? 0.f : -10000.f * F_L2E;
  } else {
    float m = -3e38f;
    for (int i = 0; i < NT; i++) m = fmaxf(m, trans[i * NT + j]);
    float s = 0.f;
    for (int i = 0; i < NT; i++) s += ex2((trans[i * NT + j] - m) * F_L2E);
    v = m * F_L2E + lg2(s);
  }
  if (lane < NP) V[lane] = -1e30f;
  barrier_lds();
  if (a) V[j] = v;
  barrier_lds();
  float vm = a ? v : -3e38f;
  for (int off = 32; off; off >>= 1) vm = fmaxf(vm, __shfl_xor(vm, off));

  if (a) {
    int c0 = (dir == 0) ? 0 : (CCH - 1);
    vIn[((size_t)(dir << 7) + c0) * NP + j] = v;
  }

  for (int it = 0; it < CCH - 1; it++) {
    int c = (dir == 0) ? it : (CCH - 1 - it);
    const float* row = Pg + ((size_t)(dir << 7) + c) * (NT * NP) + j * NP;
    float rm = rmaxG[((dir << 7) + c) * NT + j];
    float m = rm + vm;
    float s = 0.f;
#pragma unroll
    for (int k = 0; k < NP; k += 4) {
      float4 p = *(const float4*)&row[k];
      s += ex2(p.x + V[k]     - m);
      s += ex2(p.y + V[k + 1] - m);
      s += ex2(p.z + V[k + 2] - m);
      s += ex2(p.w + V[k + 3] - m);
    }
    float nv = m + lg2(s);
    if (a) V[j] = nv;
    barrier_lds();
    float x = a ? nv : -3e38f;
    for (int off = 32; off; off >>= 1) x = fmaxf(x, __shfl_xor(x, off));
    vm = x;
    int cn = (dir == 0) ? (c + 1) : (c - 1);
    if (a) vIn[((size_t)(dir << 7) + cn) * NP + j] = nv;
  }
}

__global__ void k_crf_p3(const float* __restrict__ feats,
                         const float* __restrict__ trans,
                         const float* __restrict__ vIn,
                         float* __restrict__ wsA,
                         float* __restrict__ wsB){
  int dir = blockIdx.x >> 7;
  int c   = blockIdx.x & (CCH - 1);
  int lane = threadIdx.x;           // 64, single wave
  int t0 = c * SCH;
  bool a = (lane < NT);
  int j = a ? lane : 0;
  __shared__ float A[NP];
  __shared__ float U[NP];

  float trr[NT];
  float rm = -3e38f;
#pragma unroll
  for (int k = 0; k < NT; k++) {
    float vv = (dir == 0) ? trans[j * NT + k] : trans[k * NT + j];
    trr[k] = vv * F_L2E;
    rm = fmaxf(rm, trr[k]);
  }
  if (lane < NP) { A[lane] = -1e30f; U[lane] = -1e30f; }
  float v0 = vIn[((size_t)(dir << 7) + c) * NP + j];
  barrier_lds();
  if (a) A[j] = v0;
  barrier_lds();
  float am = a ? v0 : -3e38f;
  for (int off = 32; off; off >>= 1) am = fmaxf(am, __shfl_xor(am, off));

  if (dir == 0) {
    float fe = feats[(size_t)t0 * NT + j] * F_L2E;
    for (int s = 0; s < SCH; s++) {
      int t = t0 + s;
      int tn = (t + 1 < LSEQ) ? t + 1 : LSEQ - 1;
      float fe_n = feats[(size_t)tn * NT + j] * F_L2E;
      float m = rm + am;
      float ss = 0.f;
#pragma unroll
      for (int k = 0; k < NT; k++) ss += ex2(trr[k] + A[k] - m);
      float out = m + lg2(ss) + fe;
      if (a) wsA[(size_t)t * NT + j] = out * F_LN2;
      if (a) A[j] = out;
      barrier_lds();
      float x = a ? out : -3e38f;
      for (int off = 32; off; off >>= 1) x = fmaxf(x, __shfl_xor(x, off));
      am = x;
      fe = fe_n;
    }
  } else {
    float b = v0;                    // beta_{t+1}, per-lane register
    int tfirst = t0 + SCH; if (tfirst > LSEQ - 1) tfirst = LSEQ - 1;
    float fe = feats[(size_t)tfirst * NT + j] * F_L2E;   // feat_{t+1} for first step
    for (int s = 0; s < SCH; s++) {
      int t = t0 + SCH - 1 - s;
      float fe_n = feats[(size_t)t * NT + j] * F_L2E;    // next step's feat_{t+1}
      float out;
      if (t == LSEQ - 1) {
        out = b;                     // identity factor
      } else {
        if (a) U[j] = b + fe;
        barrier_lds();
        float um = a ? U[j] : -3e38f;
        for (int off = 32; off; off >>= 1) um = fmaxf(um, __shfl_xor(um, off));
        float m = rm + um;
        float ss = 0.f;
#pragma unroll
        for (int k = 0; k < NT; k++) ss += ex2(trr[k] + U[k] - m);
        out = m + lg2(ss);
        barrier_lds();
      }
      if (a) wsB[(size_t)t * NT + j] = out * F_LN2;
      b = out;
      fe = fe_n;
    }
  }
}

// ---------------------------------------------------------------------------
// Kernel: score = alpha + beta; tags = argmax.
// ---------------------------------------------------------------------------
__global__ void k_finish(const float* __restrict__ wsA, const float* __restrict__ wsB,
                         float* __restrict__ out){
  int t = blockIdx.x * 256 + threadIdx.x;
  float m = -3e38f; int bi = 0;
  for (int i = 0; i < NT; i++) {
    float sc = wsA[(size_t)t * NT + i] + wsB[(size_t)t * NT + i];
    out[(size_t)t * NT + i] = sc;
    if (sc > m) { m = sc; bi = i; }
  }
  out[(size_t)LSEQ * NT + t] = (float)bi;
}

// ---------------------------------------------------------------------------
extern "C" void kernel_launch(void* const* d_in, const int* in_sizes, int n_in,
                              void* d_out, int out_size, void* d_ws, size_t ws_size,
                              hipStream_t stream) {
  const int*   words  = (const int*)  d_in[0];
  const float* embed  = (const float*)d_in[1];
  const float* Wih_f  = (const float*)d_in[2];
  const float* Whh_f  = (const float*)d_in[3];
  const float* b_f    = (const float*)d_in[4];
  const float* Wih_b  = (const float*)d_in[5];
  const float* Whh_b  = (const float*)d_in[6];
  const float* b_b    = (const float*)d_in[7];
  const float* W_out  = (const float*)d_in[8];
  const float* b_out  = (const float*)d_in[9];
  const float* trans  = (const float*)d_in[10];
  float* out = (float*)d_out;

  float* wsf = (float*)d_ws;
  size_t off = 0;
  float* G_f   = wsf + off; off += (size_t)LSEQ * 1024;
  float* G_b   = wsf + off; off += (size_t)LSEQ * 1024;
  float* hf    = wsf + off; off += (size_t)LSEQ * 256;
  float* hb    = wsf + off; off += (size_t)LSEQ * 256;
  float* feats = wsf + off; off += (size_t)LSEQ * NT + 16;
  float* wsA   = wsf + off; off += (size_t)LSEQ * NT + 16;
  float* wsB   = wsf + off; off += (size_t)LSEQ * NT + 16;
  float* fac   = wsf + off; off += 2048;
  int*   Wq    = (int*)(wsf + off); off += 2 * 1024 * 64;
  // CRF scan scratch overlaps G_f (dead after k_lstm)
  float* Pg    = G_f;                                   // 256 * 34*36
  float* rmaxG = G_f + 256 * (NT * NP);                 // 256 * 34
  float* vIn   = rmaxG + 256 * NT + 32;                 // 256 * 36

  k_quant<<<2048, 64, 0, stream>>>(Whh_f, Whh_b, Wq, fac);
  k_gproj<<<dim3(512, 2), 256, 0, stream>>>(words, embed, Wih_f, b_f, Wih_b, b_b, G_f, G_b);
  k_lstm<<<2, 512, 0, stream>>>(Wq, fac, G_f, G_b, hf, hb);
  k_feats<<<512, 256, 0, stream>>>(hf, hb, W_out, b_out, feats);
  k_crf_p1<<<256, 320, 0, stream>>>(feats, trans, Pg, rmaxG);
  k_crf_p2<<<2, 64, 0, stream>>>(trans, Pg, rmaxG, vIn);
  k_crf_p3<<<256, 64, 0, stream>>>(feats, trans, vIn, wsA, wsB);
  k_finish<<<32, 256, 0, stream>>>(wsA, wsB, out);
}